// Round 8
// baseline (2656.786 us; speedup 1.0000x reference)
//
#include <hip/hip_runtime.h>
#include <cstdint>
#include <cstddef>

#define Vv 50257
#define Va 50432   // V padded to multiple of 256
#define Tt 1024
#define Dd 1024
#define Hh 16
#define Ll 10
#define Ff 4096
#define Bb 2
#define Mm (Bb*Tt)   // 2048 rows

typedef float f32x4 __attribute__((ext_vector_type(4)));
typedef __bf16 bf16x8 __attribute__((ext_vector_type(8)));
typedef unsigned short u16x8 __attribute__((ext_vector_type(8)));
typedef unsigned short u16x4 __attribute__((ext_vector_type(4)));

static __device__ __forceinline__ unsigned short f2bf(float f) {
  unsigned int u = __builtin_bit_cast(unsigned int, f);
  unsigned int r = (u + 0x7FFFu + ((u >> 16) & 1u)) >> 16;  // RNE
  return (unsigned short)r;
}

static __device__ __forceinline__ f32x4 mfma16x16x32(u16x8 a, u16x8 b, f32x4 c) {
  return __builtin_amdgcn_mfma_f32_16x16x32_bf16(
      __builtin_bit_cast(bf16x8, a), __builtin_bit_cast(bf16x8, b), c, 0, 0, 0);
}

// async global->LDS, 16B per lane; LDS dest = wave-uniform base + lane*16
static __device__ __forceinline__ void async_cp16(const void* g, void* l) {
  __builtin_amdgcn_global_load_lds(
      (const __attribute__((address_space(1))) unsigned int*)g,
      (__attribute__((address_space(3))) unsigned int*)l, 16, 0, 0);
}

static __device__ __forceinline__ void barrier_sync() {
  __builtin_amdgcn_sched_barrier(0);
  __builtin_amdgcn_s_barrier();
  __builtin_amdgcn_sched_barrier(0);
}

template <int N>
static __device__ __forceinline__ void wait_vm() {
  if constexpr (N == 0)      asm volatile("s_waitcnt vmcnt(0)" ::: "memory");
  else if constexpr (N == 4) asm volatile("s_waitcnt vmcnt(4)" ::: "memory");
  else static_assert(N == 0 || N == 4, "unsupported vmcnt");
}

// ---------------- embedding + positional ----------------
__global__ __launch_bounds__(256) void embed_kernel(
    const int* __restrict__ x, const float* __restrict__ emb,
    const float* __restrict__ pos, float* __restrict__ h,
    unsigned short* __restrict__ hb) {
  int bt = blockIdx.x;
  int t = bt & (Tt - 1);
  int tok = x[bt];
  int i = threadIdx.x * 4;
  f32x4 e = *(const f32x4*)(emb + (size_t)tok * Dd + i);
  f32x4 p = *(const f32x4*)(pos + (size_t)t * Dd + i);
  f32x4 r = e + p;
  *(f32x4*)(h + (size_t)bt * Dd + i) = r;
  u16x4 rb = { f2bf(r[0]), f2bf(r[1]), f2bf(r[2]), f2bf(r[3]) };
  *(u16x4*)(hb + (size_t)bt * Dd + i) = rb;
}

// ---------------- residual add + LayerNorm (fp32), writes fp32 + bf16 ----------------
__global__ __launch_bounds__(256) void add_ln_kernel(
    const float* __restrict__ hin, const float* __restrict__ r,
    const float* __restrict__ g, const float* __restrict__ bb,
    float* __restrict__ hout, unsigned short* __restrict__ hbout) {
  int row = blockIdx.x;
  int tid = threadIdx.x;
  size_t off = (size_t)row * Dd + tid * 4;
  f32x4 xv = *(const f32x4*)(hin + off);
  if (r) xv += *(const f32x4*)(r + off);
  float s  = xv[0] + xv[1] + xv[2] + xv[3];
  float ss = xv[0]*xv[0] + xv[1]*xv[1] + xv[2]*xv[2] + xv[3]*xv[3];
  #pragma unroll
  for (int o = 1; o < 64; o <<= 1) {
    s  += __shfl_xor(s, o);
    ss += __shfl_xor(ss, o);
  }
  __shared__ float red[8];
  int wave = tid >> 6, lane = tid & 63;
  if (lane == 0) { red[wave] = s; red[4 + wave] = ss; }
  __syncthreads();
  s  = red[0] + red[1] + red[2] + red[3];
  ss = red[4] + red[5] + red[6] + red[7];
  float mu = s * (1.0f / Dd);
  float var = ss * (1.0f / Dd) - mu * mu;
  float rstd = rsqrtf(var + 1e-5f);
  f32x4 gv = *(const f32x4*)(g + tid * 4);
  f32x4 bv = *(const f32x4*)(bb + tid * 4);
  f32x4 y;
  #pragma unroll
  for (int j = 0; j < 4; ++j) y[j] = (xv[j] - mu) * rstd * gv[j] + bv[j];
  *(f32x4*)(hout + off) = y;
  u16x4 yb = { f2bf(y[0]), f2bf(y[1]), f2bf(y[2]), f2bf(y[3]) };
  *(u16x4*)(hbout + off) = yb;
}

// ---------------- bias gather: cb[l] = [bq|bk|bv] ----------------
__global__ __launch_bounds__(256) void bias_gather_kernel(
    const float* __restrict__ bq, const float* __restrict__ bk,
    const float* __restrict__ bv, float* __restrict__ cb) {
  int l = blockIdx.x;
  int i = threadIdx.x * 4;
  f32x4 q = *(const f32x4*)(bq + (size_t)l * Dd + i);
  f32x4 k = *(const f32x4*)(bk + (size_t)l * Dd + i);
  f32x4 v = *(const f32x4*)(bv + (size_t)l * Dd + i);
  *(f32x4*)(cb + (size_t)l * 3072 + i) = q;
  *(f32x4*)(cb + (size_t)l * 3072 + 1024 + i) = k;
  *(f32x4*)(cb + (size_t)l * 3072 + 2048 + i) = v;
}

// ---------------- weight transpose + fp32->bf16: W[K][N] -> Wt[N][K], batched over z ----------------
__global__ __launch_bounds__(256) void tconv_kernel(
    const float* __restrict__ W, unsigned short* __restrict__ Wt,
    int K, int N, int Nvalid, size_t sW, size_t sWt) {
  const float* Wl = W + (size_t)blockIdx.z * sW;
  unsigned short* Wtl = Wt + (size_t)blockIdx.z * sWt;
  __shared__ unsigned short t[64][72];
  int n0 = blockIdx.x * 64, k0 = blockIdx.y * 64;
  int tx = threadIdx.x & 15, ty = threadIdx.x >> 4;  // 16x16
  #pragma unroll
  for (int i = 0; i < 4; ++i) {
    int kr = ty + i * 16;
    int nc = tx * 4;
    int gn = n0 + nc;
    f32x4 v = {0.f, 0.f, 0.f, 0.f};
    if (gn + 3 < Nvalid) {
      v = *(const f32x4*)(Wl + (size_t)(k0 + kr) * N + gn);
    } else {
      #pragma unroll
      for (int j = 0; j < 4; ++j)
        if (gn + j < Nvalid) v[j] = Wl[(size_t)(k0 + kr) * N + gn + j];
    }
    t[nc + 0][kr] = f2bf(v[0]); t[nc + 1][kr] = f2bf(v[1]);
    t[nc + 2][kr] = f2bf(v[2]); t[nc + 3][kr] = f2bf(v[3]);
  }
  __syncthreads();
  #pragma unroll
  for (int i = 0; i < 4; ++i) {
    int nr = ty + i * 16;
    u16x4 o = *(const u16x4*)&t[nr][tx * 4];
    *(u16x4*)(Wtl + (size_t)(n0 + nr) * K + k0 + tx * 4) = o;
  }
}

// ---------------- GEMM (R4-proven m97 + 2-phase dbuf): C = A * Bt^T + bias ----------------
// EPI: 0 = fp32 out, 1 = bf16 out, 2 = gelu -> bf16 out
template <int BM, int EPI>
__global__ __launch_bounds__(256) void gemm_bt(
    const unsigned short* __restrict__ A, const unsigned short* __restrict__ Bt,
    const float* __restrict__ bias, void* __restrict__ Cout,
    int Ncols, int K) {
  constexpr int NJ = (BM == 128) ? 4 : 2;
  __shared__ __align__(16) unsigned short Al[2][BM * 32];
  __shared__ __align__(16) unsigned short Bl[2][128 * 32];
  const int bm = blockIdx.x * BM;
  const int bn = blockIdx.y * 128;
  const int tid = threadIdx.x, lane = tid & 63, wave = tid >> 6;
  const int wm = (BM == 128) ? (wave >> 1) * 64 : 0;
  const int wn = (BM == 128) ? (wave & 1) * 64 : wave * 32;
  const int rowi = lane >> 2;
  const int koff = (lane & 3) * 8;

  auto stage = [&](int buf, int k0) {
    #pragma unroll
    for (int i = 0; i < BM / 64; ++i) {
      int ch = wave + i * 4;
      async_cp16(A + (size_t)(bm + ch * 16 + rowi) * K + k0 + koff, &Al[buf][ch * 512]);
    }
    #pragma unroll
    for (int i = 0; i < 2; ++i) {
      int ch = wave + i * 4;
      async_cp16(Bt + (size_t)(bn + ch * 16 + rowi) * K + k0 + koff, &Bl[buf][ch * 512]);
    }
  };

  f32x4 acc[4][NJ];
  #pragma unroll
  for (int i = 0; i < 4; ++i)
    #pragma unroll
    for (int j = 0; j < NJ; ++j) acc[i][j] = {0.f, 0.f, 0.f, 0.f};

  stage(0, 0);
  __syncthreads();
  int cur = 0;
  for (int k0 = 0; k0 < K; k0 += 32) {
    if (k0 + 32 < K) stage(cur ^ 1, k0 + 32);
    u16x8 af[4], bfr[NJ];
    #pragma unroll
    for (int i = 0; i < 4; ++i)
      af[i] = *(const u16x8*)&Al[cur][(wm + i * 16 + (lane & 15)) * 32 + (lane >> 4) * 8];
    #pragma unroll
    for (int j = 0; j < NJ; ++j)
      bfr[j] = *(const u16x8*)&Bl[cur][(wn + j * 16 + (lane & 15)) * 32 + (lane >> 4) * 8];
    #pragma unroll
    for (int i = 0; i < 4; ++i)
      #pragma unroll
      for (int j = 0; j < NJ; ++j)
        acc[i][j] = mfma16x16x32(af[i], bfr[j], acc[i][j]);
    __syncthreads();
    cur ^= 1;
  }

  float bvv[NJ];
  #pragma unroll
  for (int j = 0; j < NJ; ++j) {
    int col = bn + wn + j * 16 + (lane & 15);
    bvv[j] = (col < Ncols) ? bias[col] : 0.0f;
  }
  #pragma unroll
  for (int i = 0; i < 4; ++i) {
    #pragma unroll
    for (int rr = 0; rr < 4; ++rr) {
      int row = bm + wm + i * 16 + (lane >> 4) * 4 + rr;
      #pragma unroll
      for (int j = 0; j < NJ; ++j) {
        int col = bn + wn + j * 16 + (lane & 15);
        if (col < Ncols) {
          float val = acc[i][j][rr] + bvv[j];
          if constexpr (EPI == 0) {
            ((float*)Cout)[(size_t)row * Ncols + col] = val;
          } else if constexpr (EPI == 1) {
            ((unsigned short*)Cout)[(size_t)row * Ncols + col] = f2bf(val);
          } else {
            float gv = 0.5f * val * (1.0f + erff(val * 0.70710678f));
            ((unsigned short*)Cout)[(size_t)row * Ncols + col] = f2bf(gv);
          }
        }
      }
    }
  }
}

// ---------------- 256^2 8-phase GEMM (m201 template), fp32 out, XCD swizzle ----------------
// 512 thr = 8 waves (2M x 4N); per-wave out 128x64. K-tile = 64, split in two
// 32-k halves. LDS 128 KiB: As/Bs[2 slot][2 khalf][256 rows][32 k], 16B-slot
// XOR swizzle (slot ^= row&3) with pre-swizzled global source (both-sides).
// Counted vmcnt(4) at phases 4/8 only; never drains in-loop.
#define MMAS8(MH)                                                   \
  do {                                                              \
    __builtin_amdgcn_s_setprio(1);                                  \
    _Pragma("unroll")                                               \
    for (int i_ = 0; i_ < 4; ++i_)                                  \
      _Pragma("unroll")                                             \
      for (int j_ = 0; j_ < 4; ++j_)                                \
        acc[(MH) * 4 + i_][j_] =                                    \
            mfma16x16x32(af[i_], bfr[j_], acc[(MH) * 4 + i_][j_]);  \
    __builtin_amdgcn_s_setprio(0);                                  \
  } while (0)

__global__ __launch_bounds__(512, 1) void gemm256_8ph(
    const unsigned short* __restrict__ A, const unsigned short* __restrict__ Bt,
    const float* __restrict__ bias, float* __restrict__ C, int Ncols, int K) {
  __shared__ __align__(16) unsigned short Asl[2 * 2 * 256 * 32];
  __shared__ __align__(16) unsigned short Bsl[2 * 2 * 256 * 32];
  // bijective XCD-ownership swizzle (grid total % 8 == 0)
  const unsigned gx = gridDim.x;
  const unsigned total = gx * gridDim.y;
  const unsigned flat = blockIdx.y * gx + blockIdx.x;
  const unsigned per = total >> 3;
  const unsigned work = (flat & 7u) * per + (flat >> 3);
  const int bm = (int)(work % gx) * 256;
  const int bn = (int)(work / gx) * 256;
  const int tid = threadIdx.x, lane = tid & 63, wave = tid >> 6;
  const int wm = (wave >> 2) * 128;      // 0 / 128
  const int wn = (wave & 3) * 64;        // 0..192
  const int gsl = (lane & 3) ^ ((lane >> 2) & 3);      // staged global slot
  const int rsl = ((lane >> 4) ^ (lane & 3)) * 8;      // read slot offset (u16)

  auto stA = [&](int slot, int kh, int tile) {
    #pragma unroll
    for (int c = 0; c < 2; ++c) {
      int rb = (wave * 2 + c) * 16;
      async_cp16(A + (size_t)(bm + rb + (lane >> 2)) * K + tile * 64 + kh * 32 + gsl * 8,
                 &Asl[((slot * 2 + kh) * 256 + rb) * 32]);
    }
  };
  auto stB = [&](int slot, int kh, int tile) {
    #pragma unroll
    for (int c = 0; c < 2; ++c) {
      int rb = (wave * 2 + c) * 16;
      async_cp16(Bt + (size_t)(bn + rb + (lane >> 2)) * K + tile * 64 + kh * 32 + gsl * 8,
                 &Bsl[((slot * 2 + kh) * 256 + rb) * 32]);
    }
  };

  f32x4 acc[8][4];
  #pragma unroll
  for (int i = 0; i < 8; ++i)
    #pragma unroll
    for (int j = 0; j < 4; ++j) acc[i][j] = {0.f, 0.f, 0.f, 0.f};

  u16x8 af[4], bfr[4];
  auto ldA = [&](int slot, int kh, int mh) {
    #pragma unroll
    for (int i = 0; i < 4; ++i) {
      int r = wm + mh * 64 + i * 16 + (lane & 15);
      af[i] = *(const u16x8*)&Asl[((slot * 2 + kh) * 256 + r) * 32 + rsl];
    }
  };
  auto ldB = [&](int slot, int kh) {
    #pragma unroll
    for (int j = 0; j < 4; ++j) {
      int r = wn + j * 16 + (lane & 15);
      bfr[j] = *(const u16x8*)&Bsl[((slot * 2 + kh) * 256 + r) * 32 + rsl];
    }
  };

  const int ntiles = K >> 6;
  const int niter = ntiles >> 1;
  // prologue: tile0 fully + tile1 Kh0 (12 loads/thread); wait tile0 (8 oldest)
  stA(0, 0, 0); stB(0, 0, 0); stA(0, 1, 0); stB(0, 1, 0);
  stA(1, 0, 1); stB(1, 0, 1);
  wait_vm<4>();
  barrier_sync();

  for (int it = 0; it < niter; ++it) {
    const int te = 2 * it, to = te + 1;
    const bool last = (it == niter - 1);
    // p1: (slot0,k0,Mlo) | stage A-Kh1(to)
    ldB(0, 0); ldA(0, 0, 0); stA(1, 1, to);
    barrier_sync(); MMAS8(0); barrier_sync();
    // p2: (slot0,k0,Mhi) | stage B-Kh1(to)
    ldA(0, 0, 1); stB(1, 1, to);
    barrier_sync(); MMAS8(1); barrier_sync();
    // p3: (slot0,k1,Mlo) | stage A-Kh0(te+2)
    ldB(0, 1); ldA(0, 1, 0);
    if (!last) stA(0, 0, te + 2);
    barrier_sync(); MMAS8(0); barrier_sync();
    // p4: (slot0,k1,Mhi) | stage B-Kh0(te+2) | vmcnt
    ldA(0, 1, 1);
    if (!last) { stB(0, 0, te + 2); wait_vm<4>(); } else { wait_vm<0>(); }
    barrier_sync(); MMAS8(1); barrier_sync();
    // p5: (slot1,k0,Mlo) | stage A-Kh1(te+2)
    ldB(1, 0); ldA(1, 0, 0);
    if (!last) stA(0, 1, te + 2);
    barrier_sync(); MMAS8(0); barrier_sync();
    // p6: (slot1,k0,Mhi) | stage B-Kh1(te+2)
    ldA(1, 0, 1);
    if (!last) stB(0, 1, te + 2);
    barrier_sync(); MMAS8(1); barrier_sync();
    // p7: (slot1,k1,Mlo) | stage A-Kh0(to+2)
    ldB(1, 1); ldA(1, 1, 0);
    if (!last) stA(1, 0, to + 2);
    barrier_sync(); MMAS8(0); barrier_sync();
    // p8: (slot1,k1,Mhi) | stage B-Kh0(to+2) | vmcnt
    ldA(1, 1, 1);
    if (!last) { stB(1, 0, to + 2); wait_vm<4>(); }
    barrier_sync(); MMAS8(1); barrier_sync();
  }

  float bvv[4];
  #pragma unroll
  for (int j = 0; j < 4; ++j) {
    int col = bn + wn + j * 16 + (lane & 15);
    bvv[j] = (col < Ncols) ? bias[col] : 0.0f;
  }
  #pragma unroll
  for (int mi = 0; mi < 8; ++mi) {
    #pragma unroll
    for (int rr = 0; rr < 4; ++rr) {
      int row = bm + wm + mi * 16 + (lane >> 4) * 4 + rr;
      #pragma unroll
      for (int j = 0; j < 4; ++j) {
        int col = bn + wn + j * 16 + (lane & 15);
        if (col < Ncols)
          C[(size_t)row * Ncols + col] = acc[mi][j][rr] + bvv[j];
      }
    }
  }
}

// ---------------- legacy GEMM (fp32 B, staged convert) -- small-ws fallback ----------------
template <int EPI>
__global__ __launch_bounds__(256) void gemm_f32b(
    const unsigned short* __restrict__ A, const float* __restrict__ Bw,
    const float* __restrict__ bias, void* __restrict__ Cout, int N, int K) {
  __shared__ __align__(16) unsigned short Al[128][40];
  __shared__ __align__(16) unsigned short Btl[128][40];
  const int bn = blockIdx.x * 128;
  const int bm = blockIdx.y * 128;
  const int tid = threadIdx.x;
  const int lane = tid & 63;
  const int wave = tid >> 6;
  const int wm = (wave >> 1) * 64;
  const int wn = (wave & 1) * 64;
  const bool nfast = ((N & 3) == 0);

  f32x4 acc[4][4];
  #pragma unroll
  for (int i = 0; i < 4; ++i)
    #pragma unroll
    for (int j = 0; j < 4; ++j) acc[i][j] = {0.f, 0.f, 0.f, 0.f};

  for (int k0 = 0; k0 < K; k0 += 32) {
    __syncthreads();
    #pragma unroll
    for (int i = 0; i < 2; ++i) {
      int c = tid + i * 256;
      int row = c >> 2, ko = (c & 3) * 8;
      u16x8 v = *(const u16x8*)(A + (size_t)(bm + row) * K + k0 + ko);
      *(u16x8*)&Al[row][ko] = v;
    }
    if (nfast) {
      #pragma unroll
      for (int i = 0; i < 4; ++i) {
        int c = tid + i * 256;
        int kr = c >> 5;
        int no = (c & 31) * 4;
        f32x4 v4 = *(const f32x4*)(Bw + (size_t)(k0 + kr) * N + bn + no);
        Btl[no + 0][kr] = f2bf(v4[0]); Btl[no + 1][kr] = f2bf(v4[1]);
        Btl[no + 2][kr] = f2bf(v4[2]); Btl[no + 3][kr] = f2bf(v4[3]);
      }
    } else {
      #pragma unroll
      for (int i = 0; i < 4; ++i) {
        int c = tid + i * 256;
        int kr = c >> 5;
        int nb = c & 31;
        #pragma unroll
        for (int j = 0; j < 4; ++j) {
          int col = nb + j * 32;
          float v = (bn + col < N) ? Bw[(size_t)(k0 + kr) * N + bn + col] : 0.0f;
          Btl[col][kr] = f2bf(v);
        }
      }
    }
    __syncthreads();
    u16x8 af[4], bfr[4];
    #pragma unroll
    for (int i = 0; i < 4; ++i)
      af[i] = *(const u16x8*)&Al[wm + i * 16 + (lane & 15)][(lane >> 4) * 8];
    #pragma unroll
    for (int j = 0; j < 4; ++j)
      bfr[j] = *(const u16x8*)&Btl[wn + j * 16 + (lane & 15)][(lane >> 4) * 8];
    #pragma unroll
    for (int i = 0; i < 4; ++i)
      #pragma unroll
      for (int j = 0; j < 4; ++j)
        acc[i][j] = mfma16x16x32(af[i], bfr[j], acc[i][j]);
  }
  #pragma unroll
  for (int j = 0; j < 4; ++j) {
    int col = bn + wn + j * 16 + (lane & 15);
    bool cok = (col < N);
    float bv = cok ? bias[col] : 0.0f;
    #pragma unroll
    for (int i = 0; i < 4; ++i) {
      #pragma unroll
      for (int rr = 0; rr < 4; ++rr) {
        int row = bm + wm + i * 16 + (lane >> 4) * 4 + rr;
        float val = acc[i][j][rr] + bv;
        if (cok) {
          if constexpr (EPI == 0) ((float*)Cout)[(size_t)row * N + col] = val;
          else if constexpr (EPI == 1) ((unsigned short*)Cout)[(size_t)row * N + col] = f2bf(val);
          else {
            float gv = 0.5f * val * (1.0f + erff(val * 0.70710678f));
            ((unsigned short*)Cout)[(size_t)row * N + col] = f2bf(gv);
          }
        }
      }
    }
  }
}

// ---------------- fused causal attention (R4 version, known-good) ----------------
__global__ __launch_bounds__(256) void attn_kernel(
    const unsigned short* __restrict__ q, const unsigned short* __restrict__ k,
    const unsigned short* __restrict__ v, float* __restrict__ o, int ld) {
  const int ys = blockIdx.y;
  const int qt = (ys < 8) ? ys : 23 - ys;  // pairing remap (bijective on 0..15)
  const int bh = blockIdx.x;
  const int b = bh >> 4, h = bh & 15;
  const size_t base = (size_t)b * Tt * ld + (size_t)h * 64;
  const int tid = threadIdx.x, lane = tid & 63, wave = tid >> 6;
  const int q0 = qt * 64 + wave * 16;

  __shared__ __align__(16) unsigned short Kl[64][72];
  __shared__ __align__(16) unsigned short Vt[64][72];   // [d][kc swizzled]
  __shared__ __align__(16) unsigned short Pl[4][16][72];

  const float SC = 0.18033688011112042f;  // 0.125 * log2(e)

  u16x8 qa[2];
  {
    const unsigned short* qp = q + base + (size_t)(q0 + (lane & 15)) * ld + (lane >> 4) * 8;
    qa[0] = *(const u16x8*)qp;
    qa[1] = *(const u16x8*)(qp + 32);
  }

  f32x4 Oacc[4];
  #pragma unroll
  for (int df = 0; df < 4; ++df) Oacc[df] = {0.f, 0.f, 0.f, 0.f};
  float m_run[4], l_run[4];
  #pragma unroll
  for (int rr = 0; rr < 4; ++rr) { m_run[rr] = -__builtin_inff(); l_run[rr] = 0.f; }

  for (int kt = 0; kt <= qt; ++kt) {
    __syncthreads();
    #pragma unroll
    for (int i = 0; i < 2; ++i) {
      int c = tid + i * 256;
      int rr = c >> 3, dof = (c & 7) * 8;
      *(u16x8*)&Kl[rr][dof] =
          *(const u16x8*)(k + base + (size_t)(kt * 64 + rr) * ld + dof);
    }
    #pragma unroll
    for (int i = 0; i < 2; ++i) {
      int c = tid + i * 256;
      int rr = c >> 3, dof = (c & 7) * 8;
      u16x8 vv = *(const u16x8*)(v + base + (size_t)(kt * 64 + rr) * ld + dof);
      #pragma unroll
      for (int j = 0; j < 8; ++j) {
        int d = dof + j;
        Vt[d][(rr + (d & 56)) & 63] = vv[j];
      }
    }
    __syncthreads();

    f32x4 S[4];
    #pragma unroll
    for (int nf = 0; nf < 4; ++nf) {
      S[nf] = {0.f, 0.f, 0.f, 0.f};
      #pragma unroll
      for (int s = 0; s < 2; ++s) {
        u16x8 kb = *(const u16x8*)&Kl[nf * 16 + (lane & 15)][s * 32 + (lane >> 4) * 8];
        S[nf] = mfma16x16x32(qa[s], kb, S[nf]);
      }
    }
    const int kbase = kt * 64;
    float mx[4];
    #pragma unroll
    for (int rr = 0; rr < 4; ++rr) mx[rr] = -__builtin_inff();
    #pragma unroll
    for (int nf = 0; nf < 4; ++nf) {
      int kcol = kbase + nf * 16 + (lane & 15);
      #pragma unroll
      for (int rr = 0; rr < 4; ++rr) {
        int qrow = q0 + (lane >> 4) * 4 + rr;
        float sv = S[nf][rr] * SC;
        if (kcol > qrow) sv = -__builtin_inff();
        S[nf][rr] = sv;
        mx[rr] = fmaxf(mx[rr], sv);
      }
    }
    #pragma unroll
    for (int rr = 0; rr < 4; ++rr) {
      #pragma unroll
      for (int off = 1; off < 16; off <<= 1)
        mx[rr] = fmaxf(mx[rr], __shfl_xor(mx[rr], off));
    }
    float psum[4];
    #pragma unroll
    for (int rr = 0; rr < 4; ++rr) {
      float mnew = fmaxf(m_run[rr], mx[rr]);
      float sc = exp2f(m_run[rr] - mnew);
      l_run[rr] *= sc;
      #pragma unroll
      for (int df = 0; df < 4; ++df) Oacc[df][rr] *= sc;
      m_run[rr] = mnew;
      psum[rr] = 0.f;
    }
    #pragma unroll
    for (int nf = 0; nf < 4; ++nf) {
      #pragma unroll
      for (int rr = 0; rr < 4; ++rr) {
        float pv = exp2f(S[nf][rr] - m_run[rr]);
        S[nf][rr] = pv;
        psum[rr] += pv;
      }
    }
    #pragma unroll
    for (int rr = 0; rr < 4; ++rr) {
      #pragma unroll
      for (int off = 1; off < 16; off <<= 1) psum[rr] += __shfl_xor(psum[rr], off);
      l_run[rr] += psum[rr];
    }
    #pragma unroll
    for (int nf = 0; nf < 4; ++nf)
      #pragma unroll
      for (int rr = 0; rr < 4; ++rr)
        Pl[wave][(lane >> 4) * 4 + rr][nf * 16 + (lane & 15)] = f2bf(S[nf][rr]);
    __syncthreads();
    #pragma unroll
    for (int s = 0; s < 2; ++s) {
      u16x8 pa = *(const u16x8*)&Pl[wave][lane & 15][s * 32 + (lane >> 4) * 8];
      #pragma unroll
      for (int df = 0; df < 4; ++df) {
        int d = df * 16 + (lane & 15);
        int cs = (s * 32 + (lane >> 4) * 8 + (d & 56)) & 63;
        u16x8 vb = *(const u16x8*)&Vt[d][cs];
        Oacc[df] = mfma16x16x32(pa, vb, Oacc[df]);
      }
    }
  }

  #pragma unroll
  for (int df = 0; df < 4; ++df) {
    int d = df * 16 + (lane & 15);
    #pragma unroll
    for (int rr = 0; rr < 4; ++rr) {
      int qrow = q0 + (lane >> 4) * 4 + rr;
      o[((size_t)b * Tt + qrow) * Dd + h * 64 + d] = Oacc[df][rr] / l_run[rr];
    }
  }
}

// ---------------- host launch ----------------
extern "C" void kernel_launch(void* const* d_in, const int* in_sizes, int n_in,
                              void* d_out, int out_size, void* d_ws, size_t ws_size,
                              hipStream_t stream) {
  const int*   x     = (const int*)d_in[0];
  const float* emb   = (const float*)d_in[1];
  const float* pos   = (const float*)d_in[2];
  const float* Wq    = (const float*)d_in[3];
  const float* bq    = (const float*)d_in[4];
  const float* Wk    = (const float*)d_in[5];
  const float* bk    = (const float*)d_in[6];
  const float* Wv    = (const float*)d_in[7];
  const float* bv    = (const float*)d_in[8];
  const float* ln_g  = (const float*)d_in[9];
  const float* ln_b  = (const float*)d_in[10];
  const float* W1    = (const float*)d_in[11];
  const float* b1    = (const float*)d_in[12];
  const float* W2    = (const float*)d_in[13];
  const float* b2    = (const float*)d_in[14];
  const float* lnf_g = (const float*)d_in[15];
  const float* lnf_b = (const float*)d_in[16];
  const float* Wout  = (const float*)d_in[17];
  const float* bout  = (const float*)d_in[18];
  float* out = (float*)d_out;

  char* p = (char*)d_ws;
  auto alloc = [&](size_t bytes) {
    char* r = p; p += (bytes + 255) & ~(size_t)255; return r;
  };
  float* h           = (float*)alloc((size_t)Mm * Dd * 4);
  unsigned short* hb = (unsigned short*)alloc((size_t)Mm * Dd * 2);
  unsigned short* qkv = (unsigned short*)alloc((size_t)Mm * 3072 * 2);
  float* of          = (float*)alloc((size_t)Mm * Dd * 4);
  unsigned short* a1 = (unsigned short*)alloc((size_t)Mm * Ff * 2);
  float* cb          = (float*)alloc((size_t)Ll * 3072 * 4);
  size_t base_used = (size_t)(p - (char*)d_ws);

  const size_t SZ_WQKVT = (size_t)Ll * 3072 * Dd * 2;
  const size_t SZ_W1T   = (size_t)Ll * Ff * Dd * 2;
  const size_t SZ_W2T   = (size_t)Ll * Dd * Ff * 2;
  const size_t SZ_WOUTT = (size_t)Va * Dd * 2;
  const size_t need_big = base_used + SZ_WQKVT + SZ_W1T + SZ_W2T + SZ_WOUTT + 4096;
  const size_t need_rot = base_used + SZ_WOUTT + 4096;

  embed_kernel<<<Mm, 256, 0, stream>>>(x, emb, pos, h, hb);

  if (ws_size >= need_rot) {
    bias_gather_kernel<<<Ll, 256, 0, stream>>>(bq, bk, bv, cb);
    const bool big = (ws_size >= need_big);
    unsigned short *wqkvt, *w1t, *w2t, *woutt;
    if (big) {
      wqkvt = (unsigned short*)alloc(SZ_WQKVT);
      w1t   = (unsigned short*)alloc(SZ_W1T);
      w2t   = (unsigned short*)alloc(SZ_W2T);
      woutt = (unsigned short*)alloc(SZ_WOUTT);
      tconv_kernel<<<dim3(16, 16, Ll), 256, 0, stream>>>(
          Wq, wqkvt,           Dd, Dd, Dd, (size_t)Dd*Dd, (size_t)3072*Dd);
      tconv_kernel<<<dim3(16, 16, Ll), 256, 0, stream>>>(
          Wk, wqkvt + 1024*Dd, Dd, Dd, Dd, (size_t)Dd*Dd, (size_t)3072*Dd);
      tconv_kernel<<<dim3(16, 16, Ll), 256, 0, stream>>>(
          Wv, wqkvt + 2048*Dd, Dd, Dd, Dd, (size_t)Dd*Dd, (size_t)3072*Dd);
      tconv_kernel<<<dim3(Ff/64, Dd/64, Ll), 256, 0, stream>>>(
          W1, w1t, Dd, Ff, Ff, (size_t)Dd*Ff, (size_t)Ff*Dd);
      tconv_kernel<<<dim3(Dd/64, Ff/64, Ll), 256, 0, stream>>>(
          W2, w2t, Ff, Dd, Dd, (size_t)Ff*Dd, (size_t)Dd*Ff);
      tconv_kernel<<<dim3(Va/64, Dd/64, 1), 256, 0, stream>>>(
          Wout, woutt, Dd, Vv, Vv, 0, 0);
    } else {
      unsigned short* wbuf = (unsigned short*)alloc(SZ_WOUTT);
      wqkvt = w1t = w2t = woutt = wbuf;
    }

    for (int l = 0; l < Ll; ++l) {
      unsigned short* wq_l = big ? (wqkvt + (size_t)l * 3072 * Dd) : wqkvt;
      if (!big) {
        tconv_kernel<<<dim3(16, 16, 1), 256, 0, stream>>>(Wq + (size_t)l * Dd * Dd, wq_l,           Dd, Dd, Dd, 0, 0);
        tconv_kernel<<<dim3(16, 16, 1), 256, 0, stream>>>(Wk + (size_t)l * Dd * Dd, wq_l + 1024*Dd, Dd, Dd, Dd, 0, 0);
        tconv_kernel<<<dim3(16, 16, 1), 256, 0, stream>>>(Wv + (size_t)l * Dd * Dd, wq_l + 2048*Dd, Dd, Dd, Dd, 0, 0);
      }
      gemm_bt<128, 1><<<dim3(Mm/128, 3072/128), 256, 0, stream>>>(
          hb, wq_l, cb + (size_t)l * 3072, qkv, 3072, Dd);
      attn_kernel<<<dim3(Bb*Hh, Tt/64), 256, 0, stream>>>(qkv, qkv + 1024, qkv + 2048, of, 3072);
      add_ln_kernel<<<Mm, 256, 0, stream>>>(h, of, ln_g + (size_t)l * Dd,
                                            ln_b + (size_t)l * Dd, h, hb);
      unsigned short* w1_l = big ? (w1t + (size_t)l * Ff * Dd) : w1t;
      if (!big)
        tconv_kernel<<<dim3(Ff/64, Dd/64, 1), 256, 0, stream>>>(W1 + (size_t)l * Dd * Ff, w1_l, Dd, Ff, Ff, 0, 0);
      gemm_bt<128, 2><<<dim3(Mm/128, Ff/128), 256, 0, stream>>>(
          hb, w1_l, b1 + (size_t)l * Ff, a1, Ff, Dd);
      unsigned short* w2_l = big ? (w2t + (size_t)l * Dd * Ff) : w2t;
      if (!big)
        tconv_kernel<<<dim3(Dd/64, Ff/64, 1), 256, 0, stream>>>(W2 + (size_t)l * Ff * Dd, w2_l, Ff, Dd, Dd, 0, 0);
      gemm_bt<64, 0><<<dim3(Mm/64, Dd/128), 256, 0, stream>>>(
          a1, w2_l, b2 + (size_t)l * Dd, of, Dd, Ff);
      add_ln_kernel<<<Mm, 256, 0, stream>>>(h, of, ln_g + (size_t)l * Dd,
                                            ln_b + (size_t)l * Dd, h, hb);
    }

    add_ln_kernel<<<Mm, 256, 0, stream>>>(h, nullptr, lnf_g, lnf_b, h, hb);
    if (!big)
      tconv_kernel<<<dim3(Va/64, Dd/64, 1), 256, 0, stream>>>(Wout, woutt, Dd, Vv, Vv, 0, 0);
    gemm256_8ph<<<dim3(Mm/256, Va/256), 512, 0, stream>>>(
        hb, woutt, bout, out, Vv, Dd);
  } else {
    unsigned short* qb = qkv;
    unsigned short* kb = qkv + (size_t)Mm * Dd;
    unsigned short* vb = qkv + (size_t)2 * Mm * Dd;
    for (int l = 0; l < Ll; ++l) {
      const size_t wo = (size_t)l * Dd * Dd;
      gemm_f32b<1><<<dim3(Dd/128, Mm/128), 256, 0, stream>>>(hb, Wq + wo, bq + (size_t)l*Dd, qb, Dd, Dd);
      gemm_f32b<1><<<dim3(Dd/128, Mm/128), 256, 0, stream>>>(hb, Wk + wo, bk + (size_t)l*Dd, kb, Dd, Dd);
      gemm_f32b<1><<<dim3(Dd/128, Mm/128), 256, 0, stream>>>(hb, Wv + wo, bv + (size_t)l*Dd, vb, Dd, Dd);
      attn_kernel<<<dim3(Bb*Hh, Tt/64), 256, 0, stream>>>(qb, kb, vb, of, Dd);
      add_ln_kernel<<<Mm, 256, 0, stream>>>(h, of, ln_g + (size_t)l*Dd, ln_b + (size_t)l*Dd, h, hb);
      gemm_f32b<2><<<dim3(Ff/128, Mm/128), 256, 0, stream>>>(hb, W1 + (size_t)l*Dd*Ff, b1 + (size_t)l*Ff, a1, Ff, Dd);
      gemm_f32b<0><<<dim3(Dd/128, Mm/128), 256, 0, stream>>>(a1, W2 + (size_t)l*Ff*Dd, b2 + (size_t)l*Dd, of, Dd, Ff);
      add_ln_kernel<<<Mm, 256, 0, stream>>>(h, of, ln_g + (size_t)l*Dd, ln_b + (size_t)l*Dd, h, hb);
    }
    add_ln_kernel<<<Mm, 256, 0, stream>>>(h, nullptr, lnf_g, lnf_b, h, hb);
    gemm_f32b<0><<<dim3((Vv + 127)/128, Mm/128), 256, 0, stream>>>(hb, Wout, bout, out, Vv, Dd);
  }
}

// Round 9
// 2552.117 us; speedup vs baseline: 1.0410x; 1.0410x over previous
//
#include <hip/hip_runtime.h>
#include <cstdint>
#include <cstddef>

#define Vv 50257
#define Va 50304   // V padded to multiple of 128
#define Tt 1024
#define Dd 1024
#define Hh 16
#define Ll 10
#define Ff 4096
#define Bb 2
#define Mm (Bb*Tt)   // 2048 rows

typedef float f32x4 __attribute__((ext_vector_type(4)));
typedef __bf16 bf16x8 __attribute__((ext_vector_type(8)));
typedef unsigned short u16x8 __attribute__((ext_vector_type(8)));
typedef unsigned short u16x4 __attribute__((ext_vector_type(4)));

static __device__ __forceinline__ unsigned short f2bf(float f) {
  unsigned int u = __builtin_bit_cast(unsigned int, f);
  unsigned int r = (u + 0x7FFFu + ((u >> 16) & 1u)) >> 16;  // RNE
  return (unsigned short)r;
}

static __device__ __forceinline__ f32x4 mfma16x16x32(u16x8 a, u16x8 b, f32x4 c) {
  return __builtin_amdgcn_mfma_f32_16x16x32_bf16(
      __builtin_bit_cast(bf16x8, a), __builtin_bit_cast(bf16x8, b), c, 0, 0, 0);
}

// async global->LDS, 16B per lane; LDS dest = wave-uniform base + lane*16
static __device__ __forceinline__ void async_cp16(const void* g, void* l) {
  __builtin_amdgcn_global_load_lds(
      (const __attribute__((address_space(1))) unsigned int*)g,
      (__attribute__((address_space(3))) unsigned int*)l, 16, 0, 0);
}

// ---------------- embedding + positional ----------------
__global__ __launch_bounds__(256) void embed_kernel(
    const int* __restrict__ x, const float* __restrict__ emb,
    const float* __restrict__ pos, float* __restrict__ h,
    unsigned short* __restrict__ hb) {
  int bt = blockIdx.x;
  int t = bt & (Tt - 1);
  int tok = x[bt];
  int i = threadIdx.x * 4;
  f32x4 e = *(const f32x4*)(emb + (size_t)tok * Dd + i);
  f32x4 p = *(const f32x4*)(pos + (size_t)t * Dd + i);
  f32x4 r = e + p;
  *(f32x4*)(h + (size_t)bt * Dd + i) = r;
  u16x4 rb = { f2bf(r[0]), f2bf(r[1]), f2bf(r[2]), f2bf(r[3]) };
  *(u16x4*)(hb + (size_t)bt * Dd + i) = rb;
}

// ---------------- residual add + LayerNorm (fp32), writes fp32 + bf16 ----------------
__global__ __launch_bounds__(256) void add_ln_kernel(
    const float* __restrict__ hin, const float* __restrict__ r,
    const float* __restrict__ g, const float* __restrict__ bb,
    float* __restrict__ hout, unsigned short* __restrict__ hbout) {
  int row = blockIdx.x;
  int tid = threadIdx.x;
  size_t off = (size_t)row * Dd + tid * 4;
  f32x4 xv = *(const f32x4*)(hin + off);
  if (r) xv += *(const f32x4*)(r + off);
  float s  = xv[0] + xv[1] + xv[2] + xv[3];
  float ss = xv[0]*xv[0] + xv[1]*xv[1] + xv[2]*xv[2] + xv[3]*xv[3];
  #pragma unroll
  for (int o = 1; o < 64; o <<= 1) {
    s  += __shfl_xor(s, o);
    ss += __shfl_xor(ss, o);
  }
  __shared__ float red[8];
  int wave = tid >> 6, lane = tid & 63;
  if (lane == 0) { red[wave] = s; red[4 + wave] = ss; }
  __syncthreads();
  s  = red[0] + red[1] + red[2] + red[3];
  ss = red[4] + red[5] + red[6] + red[7];
  float mu = s * (1.0f / Dd);
  float var = ss * (1.0f / Dd) - mu * mu;
  float rstd = rsqrtf(var + 1e-5f);
  f32x4 gv = *(const f32x4*)(g + tid * 4);
  f32x4 bv = *(const f32x4*)(bb + tid * 4);
  f32x4 y;
  #pragma unroll
  for (int j = 0; j < 4; ++j) y[j] = (xv[j] - mu) * rstd * gv[j] + bv[j];
  *(f32x4*)(hout + off) = y;
  u16x4 yb = { f2bf(y[0]), f2bf(y[1]), f2bf(y[2]), f2bf(y[3]) };
  *(u16x4*)(hbout + off) = yb;
}

// ---------------- bias gather: cb[l] = [bq|bk|bv] ----------------
__global__ __launch_bounds__(256) void bias_gather_kernel(
    const float* __restrict__ bq, const float* __restrict__ bk,
    const float* __restrict__ bv, float* __restrict__ cb) {
  int l = blockIdx.x;
  int i = threadIdx.x * 4;
  f32x4 q = *(const f32x4*)(bq + (size_t)l * Dd + i);
  f32x4 k = *(const f32x4*)(bk + (size_t)l * Dd + i);
  f32x4 v = *(const f32x4*)(bv + (size_t)l * Dd + i);
  *(f32x4*)(cb + (size_t)l * 3072 + i) = q;
  *(f32x4*)(cb + (size_t)l * 3072 + 1024 + i) = k;
  *(f32x4*)(cb + (size_t)l * 3072 + 2048 + i) = v;
}

// ---------------- weight transpose + fp32->bf16: W[K][N] -> Wt[N][K], batched over z ----------------
__global__ __launch_bounds__(256) void tconv_kernel(
    const float* __restrict__ W, unsigned short* __restrict__ Wt,
    int K, int N, int Nvalid, size_t sW, size_t sWt) {
  const float* Wl = W + (size_t)blockIdx.z * sW;
  unsigned short* Wtl = Wt + (size_t)blockIdx.z * sWt;
  __shared__ unsigned short t[64][72];
  int n0 = blockIdx.x * 64, k0 = blockIdx.y * 64;
  int tx = threadIdx.x & 15, ty = threadIdx.x >> 4;  // 16x16
  #pragma unroll
  for (int i = 0; i < 4; ++i) {
    int kr = ty + i * 16;
    int nc = tx * 4;
    int gn = n0 + nc;
    f32x4 v = {0.f, 0.f, 0.f, 0.f};
    if (gn + 3 < Nvalid) {
      v = *(const f32x4*)(Wl + (size_t)(k0 + kr) * N + gn);
    } else {
      #pragma unroll
      for (int j = 0; j < 4; ++j)
        if (gn + j < Nvalid) v[j] = Wl[(size_t)(k0 + kr) * N + gn + j];
    }
    t[nc + 0][kr] = f2bf(v[0]); t[nc + 1][kr] = f2bf(v[1]);
    t[nc + 2][kr] = f2bf(v[2]); t[nc + 3][kr] = f2bf(v[3]);
  }
  __syncthreads();
  #pragma unroll
  for (int i = 0; i < 4; ++i) {
    int nr = ty + i * 16;
    u16x4 o = *(const u16x4*)&t[nr][tx * 4];
    *(u16x4*)(Wtl + (size_t)(n0 + nr) * K + k0 + tx * 4) = o;
  }
}

// ---------------- GEMM (m97 + 2-phase dbuf), generic wave tiling ----------------
// C[M,Ncols] = A[M][K](bf16) * Bt[N][K](bf16)^T + bias.
// grid (M/BM, ceil(N/BN)); 256 threads = 4 waves arranged WR x WC;
// per-wave output (BM/WR) x (BN/WC). SWZ: bijective XCD-ownership swizzle
// (grid total % 8 == 0) for >L3 working sets (logits).
// EPI: 0 = fp32 out, 1 = bf16 out, 2 = gelu -> bf16 out
template <int BM, int BN, int WR, int WC, int EPI, bool SWZ>
__global__ __launch_bounds__(256) void gemm_bt(
    const unsigned short* __restrict__ A, const unsigned short* __restrict__ Bt,
    const float* __restrict__ bias, void* __restrict__ Cout,
    int Ncols, int K) {
  static_assert(WR * WC == 4, "4 waves");
  constexpr int MI = BM / WR / 16;
  constexpr int NJ = BN / WC / 16;
  __shared__ __align__(16) unsigned short Al[2][BM * 32];
  __shared__ __align__(16) unsigned short Bl[2][BN * 32];
  int bx = blockIdx.x, by = blockIdx.y;
  if constexpr (SWZ) {
    unsigned gx = gridDim.x;
    unsigned total = gx * gridDim.y;
    unsigned flat = by * gx + bx;           // dispatch order (x fastest)
    unsigned per = total >> 3;
    unsigned work = (flat & 7u) * per + (flat >> 3);
    bx = work % gx; by = work / gx;
  }
  const int bm = bx * BM;
  const int bn = by * BN;
  const int tid = threadIdx.x, lane = tid & 63, wave = tid >> 6;
  const int wm = (wave / WC) * (BM / WR);
  const int wn = (wave % WC) * (BN / WC);
  const int rowi = lane >> 2;          // row within 16-row chunk
  const int koff = (lane & 3) * 8;     // k elements (16B)

  auto stage = [&](int buf, int k0) {
    #pragma unroll
    for (int i = 0; i < BM / 64; ++i) {
      int ch = wave + i * 4;
      async_cp16(A + (size_t)(bm + ch * 16 + rowi) * K + k0 + koff, &Al[buf][ch * 512]);
    }
    #pragma unroll
    for (int i = 0; i < BN / 64; ++i) {
      int ch = wave + i * 4;
      async_cp16(Bt + (size_t)(bn + ch * 16 + rowi) * K + k0 + koff, &Bl[buf][ch * 512]);
    }
  };

  f32x4 acc[MI][NJ];
  #pragma unroll
  for (int i = 0; i < MI; ++i)
    #pragma unroll
    for (int j = 0; j < NJ; ++j) acc[i][j] = {0.f, 0.f, 0.f, 0.f};

  stage(0, 0);
  __syncthreads();            // implicit vmcnt(0): tile 0 resident
  int cur = 0;
  for (int k0 = 0; k0 < K; k0 += 32) {
    if (k0 + 32 < K) stage(cur ^ 1, k0 + 32);  // prefetch flies under ds_read+MFMA
    u16x8 af[MI], bfr[NJ];
    #pragma unroll
    for (int i = 0; i < MI; ++i)
      af[i] = *(const u16x8*)&Al[cur][(wm + i * 16 + (lane & 15)) * 32 + (lane >> 4) * 8];
    #pragma unroll
    for (int j = 0; j < NJ; ++j)
      bfr[j] = *(const u16x8*)&Bl[cur][(wn + j * 16 + (lane & 15)) * 32 + (lane >> 4) * 8];
    #pragma unroll
    for (int i = 0; i < MI; ++i)
      #pragma unroll
      for (int j = 0; j < NJ; ++j)
        acc[i][j] = mfma16x16x32(af[i], bfr[j], acc[i][j]);
    __syncthreads();          // drains vmcnt(0) (next tile landed) + read-safety
    cur ^= 1;
  }

  // epilogue: C/D layout col=lane&15, row=(lane>>4)*4+reg
  float bvv[NJ];
  #pragma unroll
  for (int j = 0; j < NJ; ++j) {
    int col = bn + wn + j * 16 + (lane & 15);
    bvv[j] = (col < Ncols) ? bias[col] : 0.0f;
  }
  #pragma unroll
  for (int i = 0; i < MI; ++i) {
    #pragma unroll
    for (int rr = 0; rr < 4; ++rr) {
      int row = bm + wm + i * 16 + (lane >> 4) * 4 + rr;
      #pragma unroll
      for (int j = 0; j < NJ; ++j) {
        int col = bn + wn + j * 16 + (lane & 15);
        if (col < Ncols) {
          float val = acc[i][j][rr] + bvv[j];
          if constexpr (EPI == 0) {
            ((float*)Cout)[(size_t)row * Ncols + col] = val;
          } else if constexpr (EPI == 1) {
            ((unsigned short*)Cout)[(size_t)row * Ncols + col] = f2bf(val);
          } else {
            float gv = 0.5f * val * (1.0f + erff(val * 0.70710678f));
            ((unsigned short*)Cout)[(size_t)row * Ncols + col] = f2bf(gv);
          }
        }
      }
    }
  }
}

// ---------------- legacy GEMM (fp32 B, staged convert) -- small-ws fallback ----------------
template <int EPI>
__global__ __launch_bounds__(256) void gemm_f32b(
    const unsigned short* __restrict__ A, const float* __restrict__ Bw,
    const float* __restrict__ bias, void* __restrict__ Cout, int N, int K) {
  __shared__ __align__(16) unsigned short Al[128][40];
  __shared__ __align__(16) unsigned short Btl[128][40];
  const int bn = blockIdx.x * 128;
  const int bm = blockIdx.y * 128;
  const int tid = threadIdx.x;
  const int lane = tid & 63;
  const int wave = tid >> 6;
  const int wm = (wave >> 1) * 64;
  const int wn = (wave & 1) * 64;
  const bool nfast = ((N & 3) == 0);

  f32x4 acc[4][4];
  #pragma unroll
  for (int i = 0; i < 4; ++i)
    #pragma unroll
    for (int j = 0; j < 4; ++j) acc[i][j] = {0.f, 0.f, 0.f, 0.f};

  for (int k0 = 0; k0 < K; k0 += 32) {
    __syncthreads();
    #pragma unroll
    for (int i = 0; i < 2; ++i) {
      int c = tid + i * 256;
      int row = c >> 2, ko = (c & 3) * 8;
      u16x8 v = *(const u16x8*)(A + (size_t)(bm + row) * K + k0 + ko);
      *(u16x8*)&Al[row][ko] = v;
    }
    if (nfast) {
      #pragma unroll
      for (int i = 0; i < 4; ++i) {
        int c = tid + i * 256;
        int kr = c >> 5;
        int no = (c & 31) * 4;
        f32x4 v4 = *(const f32x4*)(Bw + (size_t)(k0 + kr) * N + bn + no);
        Btl[no + 0][kr] = f2bf(v4[0]); Btl[no + 1][kr] = f2bf(v4[1]);
        Btl[no + 2][kr] = f2bf(v4[2]); Btl[no + 3][kr] = f2bf(v4[3]);
      }
    } else {
      #pragma unroll
      for (int i = 0; i < 4; ++i) {
        int c = tid + i * 256;
        int kr = c >> 5;
        int nb = c & 31;
        #pragma unroll
        for (int j = 0; j < 4; ++j) {
          int col = nb + j * 32;
          float v = (bn + col < N) ? Bw[(size_t)(k0 + kr) * N + bn + col] : 0.0f;
          Btl[col][kr] = f2bf(v);
        }
      }
    }
    __syncthreads();
    u16x8 af[4], bfr[4];
    #pragma unroll
    for (int i = 0; i < 4; ++i)
      af[i] = *(const u16x8*)&Al[wm + i * 16 + (lane & 15)][(lane >> 4) * 8];
    #pragma unroll
    for (int j = 0; j < 4; ++j)
      bfr[j] = *(const u16x8*)&Btl[wn + j * 16 + (lane & 15)][(lane >> 4) * 8];
    #pragma unroll
    for (int i = 0; i < 4; ++i)
      #pragma unroll
      for (int j = 0; j < 4; ++j)
        acc[i][j] = mfma16x16x32(af[i], bfr[j], acc[i][j]);
  }
  #pragma unroll
  for (int j = 0; j < 4; ++j) {
    int col = bn + wn + j * 16 + (lane & 15);
    bool cok = (col < N);
    float bv = cok ? bias[col] : 0.0f;
    #pragma unroll
    for (int i = 0; i < 4; ++i) {
      #pragma unroll
      for (int rr = 0; rr < 4; ++rr) {
        int row = bm + wm + i * 16 + (lane >> 4) * 4 + rr;
        float val = acc[i][j][rr] + bv;
        if (cok) {
          if constexpr (EPI == 0) ((float*)Cout)[(size_t)row * N + col] = val;
          else if constexpr (EPI == 1) ((unsigned short*)Cout)[(size_t)row * N + col] = f2bf(val);
          else {
            float gv = 0.5f * val * (1.0f + erff(val * 0.70710678f));
            ((unsigned short*)Cout)[(size_t)row * N + col] = f2bf(gv);
          }
        }
      }
    }
  }
}

// ---------------- fused causal attention (R4 version, known-good) ----------------
__global__ __launch_bounds__(256) void attn_kernel(
    const unsigned short* __restrict__ q, const unsigned short* __restrict__ k,
    const unsigned short* __restrict__ v, float* __restrict__ o, int ld) {
  const int ys = blockIdx.y;
  const int qt = (ys < 8) ? ys : 23 - ys;  // pairing remap (bijective on 0..15)
  const int bh = blockIdx.x;
  const int b = bh >> 4, h = bh & 15;
  const size_t base = (size_t)b * Tt * ld + (size_t)h * 64;
  const int tid = threadIdx.x, lane = tid & 63, wave = tid >> 6;
  const int q0 = qt * 64 + wave * 16;

  __shared__ __align__(16) unsigned short Kl[64][72];
  __shared__ __align__(16) unsigned short Vt[64][72];   // [d][kc swizzled]
  __shared__ __align__(16) unsigned short Pl[4][16][72];

  const float SC = 0.18033688011112042f;  // 0.125 * log2(e)

  u16x8 qa[2];
  {
    const unsigned short* qp = q + base + (size_t)(q0 + (lane & 15)) * ld + (lane >> 4) * 8;
    qa[0] = *(const u16x8*)qp;
    qa[1] = *(const u16x8*)(qp + 32);
  }

  f32x4 Oacc[4];
  #pragma unroll
  for (int df = 0; df < 4; ++df) Oacc[df] = {0.f, 0.f, 0.f, 0.f};
  float m_run[4], l_run[4];
  #pragma unroll
  for (int rr = 0; rr < 4; ++rr) { m_run[rr] = -__builtin_inff(); l_run[rr] = 0.f; }

  for (int kt = 0; kt <= qt; ++kt) {
    __syncthreads();
    #pragma unroll
    for (int i = 0; i < 2; ++i) {
      int c = tid + i * 256;
      int rr = c >> 3, dof = (c & 7) * 8;
      *(u16x8*)&Kl[rr][dof] =
          *(const u16x8*)(k + base + (size_t)(kt * 64 + rr) * ld + dof);
    }
    #pragma unroll
    for (int i = 0; i < 2; ++i) {
      int c = tid + i * 256;
      int rr = c >> 3, dof = (c & 7) * 8;
      u16x8 vv = *(const u16x8*)(v + base + (size_t)(kt * 64 + rr) * ld + dof);
      #pragma unroll
      for (int j = 0; j < 8; ++j) {
        int d = dof + j;
        Vt[d][(rr + (d & 56)) & 63] = vv[j];
      }
    }
    __syncthreads();

    f32x4 S[4];
    #pragma unroll
    for (int nf = 0; nf < 4; ++nf) {
      S[nf] = {0.f, 0.f, 0.f, 0.f};
      #pragma unroll
      for (int s = 0; s < 2; ++s) {
        u16x8 kb = *(const u16x8*)&Kl[nf * 16 + (lane & 15)][s * 32 + (lane >> 4) * 8];
        S[nf] = mfma16x16x32(qa[s], kb, S[nf]);
      }
    }
    const int kbase = kt * 64;
    float mx[4];
    #pragma unroll
    for (int rr = 0; rr < 4; ++rr) mx[rr] = -__builtin_inff();
    #pragma unroll
    for (int nf = 0; nf < 4; ++nf) {
      int kcol = kbase + nf * 16 + (lane & 15);
      #pragma unroll
      for (int rr = 0; rr < 4; ++rr) {
        int qrow = q0 + (lane >> 4) * 4 + rr;
        float sv = S[nf][rr] * SC;
        if (kcol > qrow) sv = -__builtin_inff();
        S[nf][rr] = sv;
        mx[rr] = fmaxf(mx[rr], sv);
      }
    }
    #pragma unroll
    for (int rr = 0; rr < 4; ++rr) {
      #pragma unroll
      for (int off = 1; off < 16; off <<= 1)
        mx[rr] = fmaxf(mx[rr], __shfl_xor(mx[rr], off));
    }
    float psum[4];
    #pragma unroll
    for (int rr = 0; rr < 4; ++rr) {
      float mnew = fmaxf(m_run[rr], mx[rr]);
      float sc = exp2f(m_run[rr] - mnew);
      l_run[rr] *= sc;
      #pragma unroll
      for (int df = 0; df < 4; ++df) Oacc[df][rr] *= sc;
      m_run[rr] = mnew;
      psum[rr] = 0.f;
    }
    #pragma unroll
    for (int nf = 0; nf < 4; ++nf) {
      #pragma unroll
      for (int rr = 0; rr < 4; ++rr) {
        float pv = exp2f(S[nf][rr] - m_run[rr]);
        S[nf][rr] = pv;
        psum[rr] += pv;
      }
    }
    #pragma unroll
    for (int rr = 0; rr < 4; ++rr) {
      #pragma unroll
      for (int off = 1; off < 16; off <<= 1) psum[rr] += __shfl_xor(psum[rr], off);
      l_run[rr] += psum[rr];
    }
    #pragma unroll
    for (int nf = 0; nf < 4; ++nf)
      #pragma unroll
      for (int rr = 0; rr < 4; ++rr)
        Pl[wave][(lane >> 4) * 4 + rr][nf * 16 + (lane & 15)] = f2bf(S[nf][rr]);
    __syncthreads();
    #pragma unroll
    for (int s = 0; s < 2; ++s) {
      u16x8 pa = *(const u16x8*)&Pl[wave][lane & 15][s * 32 + (lane >> 4) * 8];
      #pragma unroll
      for (int df = 0; df < 4; ++df) {
        int d = df * 16 + (lane & 15);
        int cs = (s * 32 + (lane >> 4) * 8 + (d & 56)) & 63;
        u16x8 vb = *(const u16x8*)&Vt[d][cs];
        Oacc[df] = mfma16x16x32(pa, vb, Oacc[df]);
      }
    }
  }

  #pragma unroll
  for (int df = 0; df < 4; ++df) {
    int d = df * 16 + (lane & 15);
    #pragma unroll
    for (int rr = 0; rr < 4; ++rr) {
      int qrow = q0 + (lane >> 4) * 4 + rr;
      o[((size_t)b * Tt + qrow) * Dd + h * 64 + d] = Oacc[df][rr] / l_run[rr];
    }
  }
}

// ---------------- host launch ----------------
extern "C" void kernel_launch(void* const* d_in, const int* in_sizes, int n_in,
                              void* d_out, int out_size, void* d_ws, size_t ws_size,
                              hipStream_t stream) {
  const int*   x     = (const int*)d_in[0];
  const float* emb   = (const float*)d_in[1];
  const float* pos   = (const float*)d_in[2];
  const float* Wq    = (const float*)d_in[3];
  const float* bq    = (const float*)d_in[4];
  const float* Wk    = (const float*)d_in[5];
  const float* bk    = (const float*)d_in[6];
  const float* Wv    = (const float*)d_in[7];
  const float* bv    = (const float*)d_in[8];
  const float* ln_g  = (const float*)d_in[9];
  const float* ln_b  = (const float*)d_in[10];
  const float* W1    = (const float*)d_in[11];
  const float* b1    = (const float*)d_in[12];
  const float* W2    = (const float*)d_in[13];
  const float* b2    = (const float*)d_in[14];
  const float* lnf_g = (const float*)d_in[15];
  const float* lnf_b = (const float*)d_in[16];
  const float* Wout  = (const float*)d_in[17];
  const float* bout  = (const float*)d_in[18];
  float* out = (float*)d_out;

  char* p = (char*)d_ws;
  auto alloc = [&](size_t bytes) {
    char* r = p; p += (bytes + 255) & ~(size_t)255; return r;
  };
  float* h           = (float*)alloc((size_t)Mm * Dd * 4);
  unsigned short* hb = (unsigned short*)alloc((size_t)Mm * Dd * 2);
  unsigned short* qkv = (unsigned short*)alloc((size_t)Mm * 3072 * 2);
  float* of          = (float*)alloc((size_t)Mm * Dd * 4);
  unsigned short* a1 = (unsigned short*)alloc((size_t)Mm * Ff * 2);
  float* cb          = (float*)alloc((size_t)Ll * 3072 * 4);
  size_t base_used = (size_t)(p - (char*)d_ws);

  const size_t SZ_WQKVT = (size_t)Ll * 3072 * Dd * 2;
  const size_t SZ_W1T   = (size_t)Ll * Ff * Dd * 2;
  const size_t SZ_W2T   = (size_t)Ll * Dd * Ff * 2;
  const size_t SZ_WOUTT = (size_t)Va * Dd * 2;
  const size_t need_big = base_used + SZ_WQKVT + SZ_W1T + SZ_W2T + SZ_WOUTT + 4096;
  const size_t need_rot = base_used + SZ_WOUTT + 4096;

  embed_kernel<<<Mm, 256, 0, stream>>>(x, emb, pos, h, hb);

  if (ws_size >= need_rot) {
    bias_gather_kernel<<<Ll, 256, 0, stream>>>(bq, bk, bv, cb);
    const bool big = (ws_size >= need_big);
    unsigned short *wqkvt, *w1t, *w2t, *woutt;
    if (big) {
      wqkvt = (unsigned short*)alloc(SZ_WQKVT);
      w1t   = (unsigned short*)alloc(SZ_W1T);
      w2t   = (unsigned short*)alloc(SZ_W2T);
      woutt = (unsigned short*)alloc(SZ_WOUTT);
      tconv_kernel<<<dim3(16, 16, Ll), 256, 0, stream>>>(
          Wq, wqkvt,           Dd, Dd, Dd, (size_t)Dd*Dd, (size_t)3072*Dd);
      tconv_kernel<<<dim3(16, 16, Ll), 256, 0, stream>>>(
          Wk, wqkvt + 1024*Dd, Dd, Dd, Dd, (size_t)Dd*Dd, (size_t)3072*Dd);
      tconv_kernel<<<dim3(16, 16, Ll), 256, 0, stream>>>(
          Wv, wqkvt + 2048*Dd, Dd, Dd, Dd, (size_t)Dd*Dd, (size_t)3072*Dd);
      tconv_kernel<<<dim3(Ff/64, Dd/64, Ll), 256, 0, stream>>>(
          W1, w1t, Dd, Ff, Ff, (size_t)Dd*Ff, (size_t)Ff*Dd);
      tconv_kernel<<<dim3(Dd/64, Ff/64, Ll), 256, 0, stream>>>(
          W2, w2t, Ff, Dd, Dd, (size_t)Ff*Dd, (size_t)Dd*Ff);
      tconv_kernel<<<dim3(Va/64, Dd/64, 1), 256, 0, stream>>>(
          Wout, woutt, Dd, Vv, Vv, 0, 0);
    } else {
      unsigned short* wbuf = (unsigned short*)alloc(SZ_WOUTT);
      wqkvt = w1t = w2t = woutt = wbuf;
    }

    for (int l = 0; l < Ll; ++l) {
      unsigned short* wq_l = big ? (wqkvt + (size_t)l * 3072 * Dd) : wqkvt;
      if (!big) {
        tconv_kernel<<<dim3(16, 16, 1), 256, 0, stream>>>(Wq + (size_t)l * Dd * Dd, wq_l,           Dd, Dd, Dd, 0, 0);
        tconv_kernel<<<dim3(16, 16, 1), 256, 0, stream>>>(Wk + (size_t)l * Dd * Dd, wq_l + 1024*Dd, Dd, Dd, Dd, 0, 0);
        tconv_kernel<<<dim3(16, 16, 1), 256, 0, stream>>>(Wv + (size_t)l * Dd * Dd, wq_l + 2048*Dd, Dd, Dd, Dd, 0, 0);
      }
      // QKV: 64x128 tile -> grid 32x24 = 768 blocks = 3 blocks/CU (balanced)
      gemm_bt<64, 128, 1, 4, 1, false><<<dim3(Mm/64, 3072/128), 256, 0, stream>>>(
          hb, wq_l, cb + (size_t)l * 3072, qkv, 3072, Dd);
      attn_kernel<<<dim3(Bb*Hh, Tt/64), 256, 0, stream>>>(qkv, qkv + 1024, qkv + 2048, of, 3072);
      add_ln_kernel<<<Mm, 256, 0, stream>>>(h, of, ln_g + (size_t)l * Dd,
                                            ln_b + (size_t)l * Dd, h, hb);
      unsigned short* w1_l = big ? (w1t + (size_t)l * Ff * Dd) : w1t;
      if (!big)
        tconv_kernel<<<dim3(Ff/64, Dd/64, 1), 256, 0, stream>>>(W1 + (size_t)l * Dd * Ff, w1_l, Dd, Ff, Ff, 0, 0);
      // FFN1: 128x128 -> grid 16x32 = 512 = 2/CU (balanced)
      gemm_bt<128, 128, 2, 2, 2, false><<<dim3(Mm/128, Ff/128), 256, 0, stream>>>(
          hb, w1_l, b1 + (size_t)l * Ff, a1, Ff, Dd);
      unsigned short* w2_l = big ? (w2t + (size_t)l * Dd * Ff) : w2t;
      if (!big)
        tconv_kernel<<<dim3(Dd/64, Ff/64, 1), 256, 0, stream>>>(W2 + (size_t)l * Ff * Dd, w2_l, Ff, Dd, Dd, 0, 0);
      // FFN2: 64x128 -> grid 32x8 = 256 = 1/CU (balanced)
      gemm_bt<64, 128, 1, 4, 0, false><<<dim3(Mm/64, Dd/128), 256, 0, stream>>>(
          a1, w2_l, b2 + (size_t)l * Dd, of, Dd, Ff);
      add_ln_kernel<<<Mm, 256, 0, stream>>>(h, of, ln_g + (size_t)l * Dd,
                                            ln_b + (size_t)l * Dd, h, hb);
    }

    add_ln_kernel<<<Mm, 256, 0, stream>>>(h, nullptr, lnf_g, lnf_b, h, hb);
    if (!big)
      tconv_kernel<<<dim3(Va/64, Dd/64, 1), 256, 0, stream>>>(Wout, woutt, Dd, Vv, Vv, 0, 0);
    // logits: 128x128 + XCD-ownership swizzle (grid 16x393 = 6288, %8==0)
    gemm_bt<128, 128, 2, 2, 0, true><<<dim3(Mm/128, Va/128), 256, 0, stream>>>(
        hb, woutt, bout, out, Vv, Dd);
  } else {
    unsigned short* qb = qkv;
    unsigned short* kb = qkv + (size_t)Mm * Dd;
    unsigned short* vb = qkv + (size_t)2 * Mm * Dd;
    for (int l = 0; l < Ll; ++l) {
      const size_t wo = (size_t)l * Dd * Dd;
      gemm_f32b<1><<<dim3(Dd/128, Mm/128), 256, 0, stream>>>(hb, Wq + wo, bq + (size_t)l*Dd, qb, Dd, Dd);
      gemm_f32b<1><<<dim3(Dd/128, Mm/128), 256, 0, stream>>>(hb, Wk + wo, bk + (size_t)l*Dd, kb, Dd, Dd);
      gemm_f32b<1><<<dim3(Dd/128, Mm/128), 256, 0, stream>>>(hb, Wv + wo, bv + (size_t)l*Dd, vb, Dd, Dd);
      attn_kernel<<<dim3(Bb*Hh, Tt/64), 256, 0, stream>>>(qb, kb, vb, of, Dd);
      add_ln_kernel<<<Mm, 256, 0, stream>>>(h, of, ln_g + (size_t)l*Dd, ln_b + (size_t)l*Dd, h, hb);
      gemm_f32b<2><<<dim3(Ff/128, Mm/128), 256, 0, stream>>>(hb, W1 + (size_t)l*Dd*Ff, b1 + (size_t)l*Ff, a1, Ff, Dd);
      gemm_f32b<0><<<dim3(Dd/128, Mm/128), 256, 0, stream>>>(a1, W2 + (size_t)l*Ff*Dd, b2 + (size_t)l*Dd, of, Dd, Ff);
      add_ln_kernel<<<Mm, 256, 0, stream>>>(h, of, ln_g + (size_t)l*Dd, ln_b + (size_t)l*Dd, h, hb);
    }
    add_ln_kernel<<<Mm, 256, 0, stream>>>(h, nullptr, lnf_g, lnf_b, h, hb);
    gemm_f32b<0><<<dim3((Vv + 127)/128, Mm/128), 256, 0, stream>>>(hb, Wout, bout, out, Vv, Dd);
  }
}

// Round 10
// 2324.415 us; speedup vs baseline: 1.1430x; 1.0980x over previous
//
#include <hip/hip_runtime.h>
#include <cstdint>
#include <cstddef>

#define Vv 50257
#define Va 50304   // V padded to multiple of 128
#define Tt 1024
#define Dd 1024
#define Hh 16
#define Ll 10
#define Ff 4096
#define Bb 2
#define Mm (Bb*Tt)   // 2048 rows
#define KSPLIT 4     // FFN2 split-K factor

typedef float f32x4 __attribute__((ext_vector_type(4)));
typedef __bf16 bf16x8 __attribute__((ext_vector_type(8)));
typedef unsigned short u16x8 __attribute__((ext_vector_type(8)));
typedef unsigned short u16x4 __attribute__((ext_vector_type(4)));

static __device__ __forceinline__ unsigned short f2bf(float f) {
  unsigned int u = __builtin_bit_cast(unsigned int, f);
  unsigned int r = (u + 0x7FFFu + ((u >> 16) & 1u)) >> 16;  // RNE
  return (unsigned short)r;
}

static __device__ __forceinline__ f32x4 mfma16x16x32(u16x8 a, u16x8 b, f32x4 c) {
  return __builtin_amdgcn_mfma_f32_16x16x32_bf16(
      __builtin_bit_cast(bf16x8, a), __builtin_bit_cast(bf16x8, b), c, 0, 0, 0);
}

// async global->LDS, 16B per lane; LDS dest = wave-uniform base + lane*16
static __device__ __forceinline__ void async_cp16(const void* g, void* l) {
  __builtin_amdgcn_global_load_lds(
      (const __attribute__((address_space(1))) unsigned int*)g,
      (__attribute__((address_space(3))) unsigned int*)l, 16, 0, 0);
}

// ---------------- embedding + positional ----------------
__global__ __launch_bounds__(256) void embed_kernel(
    const int* __restrict__ x, const float* __restrict__ emb,
    const float* __restrict__ pos, float* __restrict__ h,
    unsigned short* __restrict__ hb) {
  int bt = blockIdx.x;
  int t = bt & (Tt - 1);
  int tok = x[bt];
  int i = threadIdx.x * 4;
  f32x4 e = *(const f32x4*)(emb + (size_t)tok * Dd + i);
  f32x4 p = *(const f32x4*)(pos + (size_t)t * Dd + i);
  f32x4 r = e + p;
  *(f32x4*)(h + (size_t)bt * Dd + i) = r;
  u16x4 rb = { f2bf(r[0]), f2bf(r[1]), f2bf(r[2]), f2bf(r[3]) };
  *(u16x4*)(hb + (size_t)bt * Dd + i) = rb;
}

// ---------------- residual add + LayerNorm (fp32), writes fp32 + bf16 ----------------
__global__ __launch_bounds__(256) void add_ln_kernel(
    const float* __restrict__ hin, const float* __restrict__ r,
    const float* __restrict__ g, const float* __restrict__ bb,
    float* __restrict__ hout, unsigned short* __restrict__ hbout) {
  int row = blockIdx.x;
  int tid = threadIdx.x;
  size_t off = (size_t)row * Dd + tid * 4;
  f32x4 xv = *(const f32x4*)(hin + off);
  if (r) xv += *(const f32x4*)(r + off);
  float s  = xv[0] + xv[1] + xv[2] + xv[3];
  float ss = xv[0]*xv[0] + xv[1]*xv[1] + xv[2]*xv[2] + xv[3]*xv[3];
  #pragma unroll
  for (int o = 1; o < 64; o <<= 1) {
    s  += __shfl_xor(s, o);
    ss += __shfl_xor(ss, o);
  }
  __shared__ float red[8];
  int wave = tid >> 6, lane = tid & 63;
  if (lane == 0) { red[wave] = s; red[4 + wave] = ss; }
  __syncthreads();
  s  = red[0] + red[1] + red[2] + red[3];
  ss = red[4] + red[5] + red[6] + red[7];
  float mu = s * (1.0f / Dd);
  float var = ss * (1.0f / Dd) - mu * mu;
  float rstd = rsqrtf(var + 1e-5f);
  f32x4 gv = *(const f32x4*)(g + tid * 4);
  f32x4 bv = *(const f32x4*)(bb + tid * 4);
  f32x4 y;
  #pragma unroll
  for (int j = 0; j < 4; ++j) y[j] = (xv[j] - mu) * rstd * gv[j] + bv[j];
  *(f32x4*)(hout + off) = y;
  u16x4 yb = { f2bf(y[0]), f2bf(y[1]), f2bf(y[2]), f2bf(y[3]) };
  *(u16x4*)(hbout + off) = yb;
}

// ---------------- residual + split-K partial reduce + bias + LayerNorm ----------------
// xv = h + sum_{s<KSPLIT} parts[s] + bias2 ; then LN as above.
__global__ __launch_bounds__(256) void add_ln_red_kernel(
    const float* __restrict__ hin, const float* __restrict__ parts,
    const float* __restrict__ bias2,
    const float* __restrict__ g, const float* __restrict__ bb,
    float* __restrict__ hout, unsigned short* __restrict__ hbout) {
  int row = blockIdx.x;
  int tid = threadIdx.x;
  size_t off = (size_t)row * Dd + tid * 4;
  f32x4 xv = *(const f32x4*)(hin + off);
  xv += *(const f32x4*)(bias2 + tid * 4);
  #pragma unroll
  for (int s = 0; s < KSPLIT; ++s)
    xv += *(const f32x4*)(parts + (size_t)s * Mm * Dd + off);
  float s  = xv[0] + xv[1] + xv[2] + xv[3];
  float ss = xv[0]*xv[0] + xv[1]*xv[1] + xv[2]*xv[2] + xv[3]*xv[3];
  #pragma unroll
  for (int o = 1; o < 64; o <<= 1) {
    s  += __shfl_xor(s, o);
    ss += __shfl_xor(ss, o);
  }
  __shared__ float red[8];
  int wave = tid >> 6, lane = tid & 63;
  if (lane == 0) { red[wave] = s; red[4 + wave] = ss; }
  __syncthreads();
  s  = red[0] + red[1] + red[2] + red[3];
  ss = red[4] + red[5] + red[6] + red[7];
  float mu = s * (1.0f / Dd);
  float var = ss * (1.0f / Dd) - mu * mu;
  float rstd = rsqrtf(var + 1e-5f);
  f32x4 gv = *(const f32x4*)(g + tid * 4);
  f32x4 bv = *(const f32x4*)(bb + tid * 4);
  f32x4 y;
  #pragma unroll
  for (int j = 0; j < 4; ++j) y[j] = (xv[j] - mu) * rstd * gv[j] + bv[j];
  *(f32x4*)(hout + off) = y;
  u16x4 yb = { f2bf(y[0]), f2bf(y[1]), f2bf(y[2]), f2bf(y[3]) };
  *(u16x4*)(hbout + off) = yb;
}

// ---------------- bias gather: cb[l] = [bq|bk|bv] ----------------
__global__ __launch_bounds__(256) void bias_gather_kernel(
    const float* __restrict__ bq, const float* __restrict__ bk,
    const float* __restrict__ bv, float* __restrict__ cb) {
  int l = blockIdx.x;
  int i = threadIdx.x * 4;
  f32x4 q = *(const f32x4*)(bq + (size_t)l * Dd + i);
  f32x4 k = *(const f32x4*)(bk + (size_t)l * Dd + i);
  f32x4 v = *(const f32x4*)(bv + (size_t)l * Dd + i);
  *(f32x4*)(cb + (size_t)l * 3072 + i) = q;
  *(f32x4*)(cb + (size_t)l * 3072 + 1024 + i) = k;
  *(f32x4*)(cb + (size_t)l * 3072 + 2048 + i) = v;
}

// ---------------- weight transpose + fp32->bf16: W[K][N] -> Wt[N][K], batched over z ----------------
__global__ __launch_bounds__(256) void tconv_kernel(
    const float* __restrict__ W, unsigned short* __restrict__ Wt,
    int K, int N, int Nvalid, size_t sW, size_t sWt) {
  const float* Wl = W + (size_t)blockIdx.z * sW;
  unsigned short* Wtl = Wt + (size_t)blockIdx.z * sWt;
  __shared__ unsigned short t[64][72];
  int n0 = blockIdx.x * 64, k0 = blockIdx.y * 64;
  int tx = threadIdx.x & 15, ty = threadIdx.x >> 4;  // 16x16
  #pragma unroll
  for (int i = 0; i < 4; ++i) {
    int kr = ty + i * 16;
    int nc = tx * 4;
    int gn = n0 + nc;
    f32x4 v = {0.f, 0.f, 0.f, 0.f};
    if (gn + 3 < Nvalid) {
      v = *(const f32x4*)(Wl + (size_t)(k0 + kr) * N + gn);
    } else {
      #pragma unroll
      for (int j = 0; j < 4; ++j)
        if (gn + j < Nvalid) v[j] = Wl[(size_t)(k0 + kr) * N + gn + j];
    }
    t[nc + 0][kr] = f2bf(v[0]); t[nc + 1][kr] = f2bf(v[1]);
    t[nc + 2][kr] = f2bf(v[2]); t[nc + 3][kr] = f2bf(v[3]);
  }
  __syncthreads();
  #pragma unroll
  for (int i = 0; i < 4; ++i) {
    int nr = ty + i * 16;
    u16x4 o = *(const u16x4*)&t[nr][tx * 4];
    *(u16x4*)(Wtl + (size_t)(n0 + nr) * K + k0 + tx * 4) = o;
  }
}

// ---------------- GEMM (m97 + 2-phase dbuf), generic wave tiling + split-K ----------------
// C[M,Ncols] = A[M][K](bf16) * Bt[N][K](bf16)^T (+ bias unless EPI==3).
// grid (M/BM, ceil(N/BN), KS); per-block K-slice = K/KS.
// EPI: 0 = fp32+bias, 1 = bf16+bias, 2 = gelu->bf16+bias,
//      3 = fp32 PARTIAL (no bias) at Cout + blockIdx.z*zstr.
// SWZ: bijective XCD-ownership swizzle (grid total % 8 == 0), >L3 working sets.
template <int BM, int BN, int WR, int WC, int EPI, bool SWZ, int KS>
__global__ __launch_bounds__(256) void gemm_bt(
    const unsigned short* __restrict__ A, const unsigned short* __restrict__ Bt,
    const float* __restrict__ bias, void* __restrict__ Cout,
    int Ncols, int K, size_t zstr) {
  static_assert(WR * WC == 4, "4 waves");
  constexpr int MI = BM / WR / 16;
  constexpr int NJ = BN / WC / 16;
  __shared__ __align__(16) unsigned short Al[2][BM * 32];
  __shared__ __align__(16) unsigned short Bl[2][BN * 32];
  int bx = blockIdx.x, by = blockIdx.y;
  if constexpr (SWZ) {
    unsigned gx = gridDim.x;
    unsigned total = gx * gridDim.y;
    unsigned flat = by * gx + bx;           // dispatch order (x fastest)
    unsigned per = total >> 3;
    unsigned work = (flat & 7u) * per + (flat >> 3);
    bx = work % gx; by = work / gx;
  }
  const int bm = bx * BM;
  const int bn = by * BN;
  const int tid = threadIdx.x, lane = tid & 63, wave = tid >> 6;
  const int wm = (wave / WC) * (BM / WR);
  const int wn = (wave % WC) * (BN / WC);
  const int rowi = lane >> 2;          // row within 16-row chunk
  const int koff = (lane & 3) * 8;     // k elements (16B)

  auto stage = [&](int buf, int k0) {
    #pragma unroll
    for (int i = 0; i < BM / 64; ++i) {
      int ch = wave + i * 4;
      async_cp16(A + (size_t)(bm + ch * 16 + rowi) * K + k0 + koff, &Al[buf][ch * 512]);
    }
    #pragma unroll
    for (int i = 0; i < BN / 64; ++i) {
      int ch = wave + i * 4;
      async_cp16(Bt + (size_t)(bn + ch * 16 + rowi) * K + k0 + koff, &Bl[buf][ch * 512]);
    }
  };

  f32x4 acc[MI][NJ];
  #pragma unroll
  for (int i = 0; i < MI; ++i)
    #pragma unroll
    for (int j = 0; j < NJ; ++j) acc[i][j] = {0.f, 0.f, 0.f, 0.f};

  const int kbeg = (KS > 1) ? (int)blockIdx.z * (K / KS) : 0;
  const int kend = kbeg + K / KS;

  stage(0, kbeg);
  __syncthreads();            // implicit vmcnt(0): tile 0 resident
  int cur = 0;
  for (int k0 = kbeg; k0 < kend; k0 += 32) {
    if (k0 + 32 < kend) stage(cur ^ 1, k0 + 32);  // prefetch under ds_read+MFMA
    u16x8 af[MI], bfr[NJ];
    #pragma unroll
    for (int i = 0; i < MI; ++i)
      af[i] = *(const u16x8*)&Al[cur][(wm + i * 16 + (lane & 15)) * 32 + (lane >> 4) * 8];
    #pragma unroll
    for (int j = 0; j < NJ; ++j)
      bfr[j] = *(const u16x8*)&Bl[cur][(wn + j * 16 + (lane & 15)) * 32 + (lane >> 4) * 8];
    #pragma unroll
    for (int i = 0; i < MI; ++i)
      #pragma unroll
      for (int j = 0; j < NJ; ++j)
        acc[i][j] = mfma16x16x32(af[i], bfr[j], acc[i][j]);
    __syncthreads();          // drains vmcnt(0) (next tile landed) + read-safety
    cur ^= 1;
  }

  // epilogue: C/D layout col=lane&15, row=(lane>>4)*4+reg
  float bvv[NJ];
  #pragma unroll
  for (int j = 0; j < NJ; ++j) {
    if constexpr (EPI != 3) {
      int col = bn + wn + j * 16 + (lane & 15);
      bvv[j] = (col < Ncols) ? bias[col] : 0.0f;
    } else bvv[j] = 0.0f;
  }
  float* Cz = (EPI == 3) ? ((float*)Cout + (size_t)blockIdx.z * zstr) : (float*)Cout;
  #pragma unroll
  for (int i = 0; i < MI; ++i) {
    #pragma unroll
    for (int rr = 0; rr < 4; ++rr) {
      int row = bm + wm + i * 16 + (lane >> 4) * 4 + rr;
      #pragma unroll
      for (int j = 0; j < NJ; ++j) {
        int col = bn + wn + j * 16 + (lane & 15);
        if (col < Ncols) {
          float val = acc[i][j][rr] + bvv[j];
          if constexpr (EPI == 0) {
            ((float*)Cout)[(size_t)row * Ncols + col] = val;
          } else if constexpr (EPI == 1) {
            ((unsigned short*)Cout)[(size_t)row * Ncols + col] = f2bf(val);
          } else if constexpr (EPI == 2) {
            float gv = 0.5f * val * (1.0f + erff(val * 0.70710678f));
            ((unsigned short*)Cout)[(size_t)row * Ncols + col] = f2bf(gv);
          } else {
            Cz[(size_t)row * Ncols + col] = val;
          }
        }
      }
    }
  }
}

// ---------------- legacy GEMM (fp32 B, staged convert) -- small-ws fallback ----------------
template <int EPI>
__global__ __launch_bounds__(256) void gemm_f32b(
    const unsigned short* __restrict__ A, const float* __restrict__ Bw,
    const float* __restrict__ bias, void* __restrict__ Cout, int N, int K) {
  __shared__ __align__(16) unsigned short Al[128][40];
  __shared__ __align__(16) unsigned short Btl[128][40];
  const int bn = blockIdx.x * 128;
  const int bm = blockIdx.y * 128;
  const int tid = threadIdx.x;
  const int lane = tid & 63;
  const int wave = tid >> 6;
  const int wm = (wave >> 1) * 64;
  const int wn = (wave & 1) * 64;
  const bool nfast = ((N & 3) == 0);

  f32x4 acc[4][4];
  #pragma unroll
  for (int i = 0; i < 4; ++i)
    #pragma unroll
    for (int j = 0; j < 4; ++j) acc[i][j] = {0.f, 0.f, 0.f, 0.f};

  for (int k0 = 0; k0 < K; k0 += 32) {
    __syncthreads();
    #pragma unroll
    for (int i = 0; i < 2; ++i) {
      int c = tid + i * 256;
      int row = c >> 2, ko = (c & 3) * 8;
      u16x8 v = *(const u16x8*)(A + (size_t)(bm + row) * K + k0 + ko);
      *(u16x8*)&Al[row][ko] = v;
    }
    if (nfast) {
      #pragma unroll
      for (int i = 0; i < 4; ++i) {
        int c = tid + i * 256;
        int kr = c >> 5;
        int no = (c & 31) * 4;
        f32x4 v4 = *(const f32x4*)(Bw + (size_t)(k0 + kr) * N + bn + no);
        Btl[no + 0][kr] = f2bf(v4[0]); Btl[no + 1][kr] = f2bf(v4[1]);
        Btl[no + 2][kr] = f2bf(v4[2]); Btl[no + 3][kr] = f2bf(v4[3]);
      }
    } else {
      #pragma unroll
      for (int i = 0; i < 4; ++i) {
        int c = tid + i * 256;
        int kr = c >> 5;
        int nb = c & 31;
        #pragma unroll
        for (int j = 0; j < 4; ++j) {
          int col = nb + j * 32;
          float v = (bn + col < N) ? Bw[(size_t)(k0 + kr) * N + bn + col] : 0.0f;
          Btl[col][kr] = f2bf(v);
        }
      }
    }
    __syncthreads();
    u16x8 af[4], bfr[4];
    #pragma unroll
    for (int i = 0; i < 4; ++i)
      af[i] = *(const u16x8*)&Al[wm + i * 16 + (lane & 15)][(lane >> 4) * 8];
    #pragma unroll
    for (int j = 0; j < 4; ++j)
      bfr[j] = *(const u16x8*)&Btl[wn + j * 16 + (lane & 15)][(lane >> 4) * 8];
    #pragma unroll
    for (int i = 0; i < 4; ++i)
      #pragma unroll
      for (int j = 0; j < 4; ++j)
        acc[i][j] = mfma16x16x32(af[i], bfr[j], acc[i][j]);
  }
  #pragma unroll
  for (int j = 0; j < 4; ++j) {
    int col = bn + wn + j * 16 + (lane & 15);
    bool cok = (col < N);
    float bv = cok ? bias[col] : 0.0f;
    #pragma unroll
    for (int i = 0; i < 4; ++i) {
      #pragma unroll
      for (int rr = 0; rr < 4; ++rr) {
        int row = bm + wm + i * 16 + (lane >> 4) * 4 + rr;
        float val = acc[i][j][rr] + bv;
        if (cok) {
          if constexpr (EPI == 0) ((float*)Cout)[(size_t)row * N + col] = val;
          else if constexpr (EPI == 1) ((unsigned short*)Cout)[(size_t)row * N + col] = f2bf(val);
          else {
            float gv = 0.5f * val * (1.0f + erff(val * 0.70710678f));
            ((unsigned short*)Cout)[(size_t)row * N + col] = f2bf(gv);
          }
        }
      }
    }
  }
}

// ---------------- fused causal attention (R4 version, known-good) ----------------
__global__ __launch_bounds__(256) void attn_kernel(
    const unsigned short* __restrict__ q, const unsigned short* __restrict__ k,
    const unsigned short* __restrict__ v, float* __restrict__ o, int ld) {
  const int ys = blockIdx.y;
  const int qt = (ys < 8) ? ys : 23 - ys;  // pairing remap (bijective on 0..15)
  const int bh = blockIdx.x;
  const int b = bh >> 4, h = bh & 15;
  const size_t base = (size_t)b * Tt * ld + (size_t)h * 64;
  const int tid = threadIdx.x, lane = tid & 63, wave = tid >> 6;
  const int q0 = qt * 64 + wave * 16;

  __shared__ __align__(16) unsigned short Kl[64][72];
  __shared__ __align__(16) unsigned short Vt[64][72];   // [d][kc swizzled]
  __shared__ __align__(16) unsigned short Pl[4][16][72];

  const float SC = 0.18033688011112042f;  // 0.125 * log2(e)

  u16x8 qa[2];
  {
    const unsigned short* qp = q + base + (size_t)(q0 + (lane & 15)) * ld + (lane >> 4) * 8;
    qa[0] = *(const u16x8*)qp;
    qa[1] = *(const u16x8*)(qp + 32);
  }

  f32x4 Oacc[4];
  #pragma unroll
  for (int df = 0; df < 4; ++df) Oacc[df] = {0.f, 0.f, 0.f, 0.f};
  float m_run[4], l_run[4];
  #pragma unroll
  for (int rr = 0; rr < 4; ++rr) { m_run[rr] = -__builtin_inff(); l_run[rr] = 0.f; }

  for (int kt = 0; kt <= qt; ++kt) {
    __syncthreads();
    #pragma unroll
    for (int i = 0; i < 2; ++i) {
      int c = tid + i * 256;
      int rr = c >> 3, dof = (c & 7) * 8;
      *(u16x8*)&Kl[rr][dof] =
          *(const u16x8*)(k + base + (size_t)(kt * 64 + rr) * ld + dof);
    }
    #pragma unroll
    for (int i = 0; i < 2; ++i) {
      int c = tid + i * 256;
      int rr = c >> 3, dof = (c & 7) * 8;
      u16x8 vv = *(const u16x8*)(v + base + (size_t)(kt * 64 + rr) * ld + dof);
      #pragma unroll
      for (int j = 0; j < 8; ++j) {
        int d = dof + j;
        Vt[d][(rr + (d & 56)) & 63] = vv[j];
      }
    }
    __syncthreads();

    f32x4 S[4];
    #pragma unroll
    for (int nf = 0; nf < 4; ++nf) {
      S[nf] = {0.f, 0.f, 0.f, 0.f};
      #pragma unroll
      for (int s = 0; s < 2; ++s) {
        u16x8 kb = *(const u16x8*)&Kl[nf * 16 + (lane & 15)][s * 32 + (lane >> 4) * 8];
        S[nf] = mfma16x16x32(qa[s], kb, S[nf]);
      }
    }
    const int kbase = kt * 64;
    float mx[4];
    #pragma unroll
    for (int rr = 0; rr < 4; ++rr) mx[rr] = -__builtin_inff();
    #pragma unroll
    for (int nf = 0; nf < 4; ++nf) {
      int kcol = kbase + nf * 16 + (lane & 15);
      #pragma unroll
      for (int rr = 0; rr < 4; ++rr) {
        int qrow = q0 + (lane >> 4) * 4 + rr;
        float sv = S[nf][rr] * SC;
        if (kcol > qrow) sv = -__builtin_inff();
        S[nf][rr] = sv;
        mx[rr] = fmaxf(mx[rr], sv);
      }
    }
    #pragma unroll
    for (int rr = 0; rr < 4; ++rr) {
      #pragma unroll
      for (int off = 1; off < 16; off <<= 1)
        mx[rr] = fmaxf(mx[rr], __shfl_xor(mx[rr], off));
    }
    float psum[4];
    #pragma unroll
    for (int rr = 0; rr < 4; ++rr) {
      float mnew = fmaxf(m_run[rr], mx[rr]);
      float sc = exp2f(m_run[rr] - mnew);
      l_run[rr] *= sc;
      #pragma unroll
      for (int df = 0; df < 4; ++df) Oacc[df][rr] *= sc;
      m_run[rr] = mnew;
      psum[rr] = 0.f;
    }
    #pragma unroll
    for (int nf = 0; nf < 4; ++nf) {
      #pragma unroll
      for (int rr = 0; rr < 4; ++rr) {
        float pv = exp2f(S[nf][rr] - m_run[rr]);
        S[nf][rr] = pv;
        psum[rr] += pv;
      }
    }
    #pragma unroll
    for (int rr = 0; rr < 4; ++rr) {
      #pragma unroll
      for (int off = 1; off < 16; off <<= 1) psum[rr] += __shfl_xor(psum[rr], off);
      l_run[rr] += psum[rr];
    }
    #pragma unroll
    for (int nf = 0; nf < 4; ++nf)
      #pragma unroll
      for (int rr = 0; rr < 4; ++rr)
        Pl[wave][(lane >> 4) * 4 + rr][nf * 16 + (lane & 15)] = f2bf(S[nf][rr]);
    __syncthreads();
    #pragma unroll
    for (int s = 0; s < 2; ++s) {
      u16x8 pa = *(const u16x8*)&Pl[wave][lane & 15][s * 32 + (lane >> 4) * 8];
      #pragma unroll
      for (int df = 0; df < 4; ++df) {
        int d = df * 16 + (lane & 15);
        int cs = (s * 32 + (lane >> 4) * 8 + (d & 56)) & 63;
        u16x8 vb = *(const u16x8*)&Vt[d][cs];
        Oacc[df] = mfma16x16x32(pa, vb, Oacc[df]);
      }
    }
  }

  #pragma unroll
  for (int df = 0; df < 4; ++df) {
    int d = df * 16 + (lane & 15);
    #pragma unroll
    for (int rr = 0; rr < 4; ++rr) {
      int qrow = q0 + (lane >> 4) * 4 + rr;
      o[((size_t)b * Tt + qrow) * Dd + h * 64 + d] = Oacc[df][rr] / l_run[rr];
    }
  }
}

// ---------------- host launch ----------------
extern "C" void kernel_launch(void* const* d_in, const int* in_sizes, int n_in,
                              void* d_out, int out_size, void* d_ws, size_t ws_size,
                              hipStream_t stream) {
  const int*   x     = (const int*)d_in[0];
  const float* emb   = (const float*)d_in[1];
  const float* pos   = (const float*)d_in[2];
  const float* Wq    = (const float*)d_in[3];
  const float* bq    = (const float*)d_in[4];
  const float* Wk    = (const float*)d_in[5];
  const float* bk    = (const float*)d_in[6];
  const float* Wv    = (const float*)d_in[7];
  const float* bv    = (const float*)d_in[8];
  const float* ln_g  = (const float*)d_in[9];
  const float* ln_b  = (const float*)d_in[10];
  const float* W1    = (const float*)d_in[11];
  const float* b1    = (const float*)d_in[12];
  const float* W2    = (const float*)d_in[13];
  const float* b2    = (const float*)d_in[14];
  const float* lnf_g = (const float*)d_in[15];
  const float* lnf_b = (const float*)d_in[16];
  const float* Wout  = (const float*)d_in[17];
  const float* bout  = (const float*)d_in[18];
  float* out = (float*)d_out;

  char* p = (char*)d_ws;
  auto alloc = [&](size_t bytes) {
    char* r = p; p += (bytes + 255) & ~(size_t)255; return r;
  };
  float* h           = (float*)alloc((size_t)Mm * Dd * 4);
  unsigned short* hb = (unsigned short*)alloc((size_t)Mm * Dd * 2);
  unsigned short* qkv = (unsigned short*)alloc((size_t)Mm * 3072 * 2);
  float* of          = (float*)alloc((size_t)Mm * Dd * 4);
  unsigned short* a1 = (unsigned short*)alloc((size_t)Mm * Ff * 2);
  float* cb          = (float*)alloc((size_t)Ll * 3072 * 4);
  float* parts       = (float*)alloc((size_t)KSPLIT * Mm * Dd * 4);  // FFN2 split-K
  size_t base_used = (size_t)(p - (char*)d_ws);

  const size_t SZ_WQKVT = (size_t)Ll * 3072 * Dd * 2;
  const size_t SZ_W1T   = (size_t)Ll * Ff * Dd * 2;
  const size_t SZ_W2T   = (size_t)Ll * Dd * Ff * 2;
  const size_t SZ_WOUTT = (size_t)Va * Dd * 2;
  const size_t need_big = base_used + SZ_WQKVT + SZ_W1T + SZ_W2T + SZ_WOUTT + 4096;
  const size_t need_rot = base_used + SZ_WOUTT + 4096;

  embed_kernel<<<Mm, 256, 0, stream>>>(x, emb, pos, h, hb);

  if (ws_size >= need_rot) {
    bias_gather_kernel<<<Ll, 256, 0, stream>>>(bq, bk, bv, cb);
    const bool big = (ws_size >= need_big);
    unsigned short *wqkvt, *w1t, *w2t, *woutt;
    if (big) {
      wqkvt = (unsigned short*)alloc(SZ_WQKVT);
      w1t   = (unsigned short*)alloc(SZ_W1T);
      w2t   = (unsigned short*)alloc(SZ_W2T);
      woutt = (unsigned short*)alloc(SZ_WOUTT);
      tconv_kernel<<<dim3(16, 16, Ll), 256, 0, stream>>>(
          Wq, wqkvt,           Dd, Dd, Dd, (size_t)Dd*Dd, (size_t)3072*Dd);
      tconv_kernel<<<dim3(16, 16, Ll), 256, 0, stream>>>(
          Wk, wqkvt + 1024*Dd, Dd, Dd, Dd, (size_t)Dd*Dd, (size_t)3072*Dd);
      tconv_kernel<<<dim3(16, 16, Ll), 256, 0, stream>>>(
          Wv, wqkvt + 2048*Dd, Dd, Dd, Dd, (size_t)Dd*Dd, (size_t)3072*Dd);
      tconv_kernel<<<dim3(Ff/64, Dd/64, Ll), 256, 0, stream>>>(
          W1, w1t, Dd, Ff, Ff, (size_t)Dd*Ff, (size_t)Ff*Dd);
      tconv_kernel<<<dim3(Dd/64, Ff/64, Ll), 256, 0, stream>>>(
          W2, w2t, Ff, Dd, Dd, (size_t)Ff*Dd, (size_t)Dd*Ff);
      tconv_kernel<<<dim3(Va/64, Dd/64, 1), 256, 0, stream>>>(
          Wout, woutt, Dd, Vv, Vv, 0, 0);
    } else {
      unsigned short* wbuf = (unsigned short*)alloc(SZ_WOUTT);
      wqkvt = w1t = w2t = woutt = wbuf;
    }

    for (int l = 0; l < Ll; ++l) {
      unsigned short* wq_l = big ? (wqkvt + (size_t)l * 3072 * Dd) : wqkvt;
      if (!big) {
        tconv_kernel<<<dim3(16, 16, 1), 256, 0, stream>>>(Wq + (size_t)l * Dd * Dd, wq_l,           Dd, Dd, Dd, 0, 0);
        tconv_kernel<<<dim3(16, 16, 1), 256, 0, stream>>>(Wk + (size_t)l * Dd * Dd, wq_l + 1024*Dd, Dd, Dd, Dd, 0, 0);
        tconv_kernel<<<dim3(16, 16, 1), 256, 0, stream>>>(Wv + (size_t)l * Dd * Dd, wq_l + 2048*Dd, Dd, Dd, Dd, 0, 0);
      }
      // QKV: 128x128 (R4 config), grid 16x24 = 384 blocks
      gemm_bt<128, 128, 2, 2, 1, false, 1><<<dim3(Mm/128, 3072/128), 256, 0, stream>>>(
          hb, wq_l, cb + (size_t)l * 3072, qkv, 3072, Dd, 0);
      attn_kernel<<<dim3(Bb*Hh, Tt/64), 256, 0, stream>>>(qkv, qkv + 1024, qkv + 2048, of, 3072);
      add_ln_kernel<<<Mm, 256, 0, stream>>>(h, of, ln_g + (size_t)l * Dd,
                                            ln_b + (size_t)l * Dd, h, hb);
      unsigned short* w1_l = big ? (w1t + (size_t)l * Ff * Dd) : w1t;
      if (!big)
        tconv_kernel<<<dim3(Ff/64, Dd/64, 1), 256, 0, stream>>>(W1 + (size_t)l * Dd * Ff, w1_l, Dd, Ff, Ff, 0, 0);
      // FFN1: 128x128, grid 16x32 = 512 blocks
      gemm_bt<128, 128, 2, 2, 2, false, 1><<<dim3(Mm/128, Ff/128), 256, 0, stream>>>(
          hb, w1_l, b1 + (size_t)l * Ff, a1, Ff, Dd, 0);
      unsigned short* w2_l = big ? (w2t + (size_t)l * Dd * Ff) : w2t;
      if (!big)
        tconv_kernel<<<dim3(Dd/64, Ff/64, 1), 256, 0, stream>>>(W2 + (size_t)l * Ff * Dd, w2_l, Ff, Dd, Dd, 0, 0);
      // FFN2: split-K=4, 128x128 tiles, grid 16x8x4 = 512 blocks, K=1024/slice
      gemm_bt<128, 128, 2, 2, 3, false, KSPLIT><<<dim3(Mm/128, Dd/128, KSPLIT), 256, 0, stream>>>(
          a1, w2_l, nullptr, parts, Dd, Ff, (size_t)Mm * Dd);
      // fused: h = LN(h + sum(parts) + b2)
      add_ln_red_kernel<<<Mm, 256, 0, stream>>>(h, parts, b2 + (size_t)l * Dd,
                                                ln_g + (size_t)l * Dd,
                                                ln_b + (size_t)l * Dd, h, hb);
    }

    add_ln_kernel<<<Mm, 256, 0, stream>>>(h, nullptr, lnf_g, lnf_b, h, hb);
    if (!big)
      tconv_kernel<<<dim3(Va/64, Dd/64, 1), 256, 0, stream>>>(Wout, woutt, Dd, Vv, Vv, 0, 0);
    // logits: 128x128 + XCD-ownership swizzle (grid 16x393 = 6288, %8==0)
    gemm_bt<128, 128, 2, 2, 0, true, 1><<<dim3(Mm/128, Va/128), 256, 0, stream>>>(
        hb, woutt, bout, out, Vv, Dd, 0);
  } else {
    unsigned short* qb = qkv;
    unsigned short* kb = qkv + (size_t)Mm * Dd;
    unsigned short* vb = qkv + (size_t)2 * Mm * Dd;
    for (int l = 0; l < Ll; ++l) {
      const size_t wo = (size_t)l * Dd * Dd;
      gemm_f32b<1><<<dim3(Dd/128, Mm/128), 256, 0, stream>>>(hb, Wq + wo, bq + (size_t)l*Dd, qb, Dd, Dd);
      gemm_f32b<1><<<dim3(Dd/128, Mm/128), 256, 0, stream>>>(hb, Wk + wo, bk + (size_t)l*Dd, kb, Dd, Dd);
      gemm_f32b<1><<<dim3(Dd/128, Mm/128), 256, 0, stream>>>(hb, Wv + wo, bv + (size_t)l*Dd, vb, Dd, Dd);
      attn_kernel<<<dim3(Bb*Hh, Tt/64), 256, 0, stream>>>(qb, kb, vb, of, Dd);
      add_ln_kernel<<<Mm, 256, 0, stream>>>(h, of, ln_g + (size_t)l*Dd, ln_b + (size_t)l*Dd, h, hb);
      gemm_f32b<2><<<dim3(Ff/128, Mm/128), 256, 0, stream>>>(hb, W1 + (size_t)l*Dd*Ff, b1 + (size_t)l*Ff, a1, Ff, Dd);
      gemm_f32b<0><<<dim3(Dd/128, Mm/128), 256, 0, stream>>>(a1, W2 + (size_t)l*Ff*Dd, b2 + (size_t)l*Dd, of, Dd, Ff);
      add_ln_kernel<<<Mm, 256, 0, stream>>>(h, of, ln_g + (size_t)l*Dd, ln_b + (size_t)l*Dd, h, hb);
    }
    add_ln_kernel<<<Mm, 256, 0, stream>>>(h, nullptr, lnf_g, lnf_b, h, hb);
    gemm_f32b<0><<<dim3((Vv + 127)/128, Mm/128), 256, 0, stream>>>(hb, Wout, bout, out, Vv, Dd);
  }
}

// Round 11
// 2265.011 us; speedup vs baseline: 1.1730x; 1.0262x over previous
//
#include <hip/hip_runtime.h>
#include <cstdint>
#include <cstddef>

#define Vv 50257
#define Va 50304   // V padded to multiple of 128
#define Tt 1024
#define Dd 1024
#define Hh 16
#define Ll 10
#define Ff 4096
#define Bb 2
#define Mm (Bb*Tt)   // 2048 rows
#define KSPLIT 4     // FFN2 split-K factor
#define QSPLIT 2     // QKV split-K factor

typedef float f32x4 __attribute__((ext_vector_type(4)));
typedef __bf16 bf16x8 __attribute__((ext_vector_type(8)));
typedef unsigned short u16x8 __attribute__((ext_vector_type(8)));
typedef unsigned short u16x4 __attribute__((ext_vector_type(4)));

static __device__ __forceinline__ unsigned short f2bf(float f) {
  unsigned int u = __builtin_bit_cast(unsigned int, f);
  unsigned int r = (u + 0x7FFFu + ((u >> 16) & 1u)) >> 16;  // RNE
  return (unsigned short)r;
}

static __device__ __forceinline__ f32x4 mfma16x16x32(u16x8 a, u16x8 b, f32x4 c) {
  return __builtin_amdgcn_mfma_f32_16x16x32_bf16(
      __builtin_bit_cast(bf16x8, a), __builtin_bit_cast(bf16x8, b), c, 0, 0, 0);
}

// async global->LDS, 16B per lane; LDS dest = wave-uniform base + lane*16
static __device__ __forceinline__ void async_cp16(const void* g, void* l) {
  __builtin_amdgcn_global_load_lds(
      (const __attribute__((address_space(1))) unsigned int*)g,
      (__attribute__((address_space(3))) unsigned int*)l, 16, 0, 0);
}

// ---------------- embedding + positional ----------------
__global__ __launch_bounds__(256) void embed_kernel(
    const int* __restrict__ x, const float* __restrict__ emb,
    const float* __restrict__ pos, float* __restrict__ h,
    unsigned short* __restrict__ hb) {
  int bt = blockIdx.x;
  int t = bt & (Tt - 1);
  int tok = x[bt];
  int i = threadIdx.x * 4;
  f32x4 e = *(const f32x4*)(emb + (size_t)tok * Dd + i);
  f32x4 p = *(const f32x4*)(pos + (size_t)t * Dd + i);
  f32x4 r = e + p;
  *(f32x4*)(h + (size_t)bt * Dd + i) = r;
  u16x4 rb = { f2bf(r[0]), f2bf(r[1]), f2bf(r[2]), f2bf(r[3]) };
  *(u16x4*)(hb + (size_t)bt * Dd + i) = rb;
}

// ---------------- residual add + LayerNorm (fp32), writes fp32 + bf16 ----------------
__global__ __launch_bounds__(256) void add_ln_kernel(
    const float* __restrict__ hin, const float* __restrict__ r,
    const float* __restrict__ g, const float* __restrict__ bb,
    float* __restrict__ hout, unsigned short* __restrict__ hbout) {
  int row = blockIdx.x;
  int tid = threadIdx.x;
  size_t off = (size_t)row * Dd + tid * 4;
  f32x4 xv = *(const f32x4*)(hin + off);
  if (r) xv += *(const f32x4*)(r + off);
  float s  = xv[0] + xv[1] + xv[2] + xv[3];
  float ss = xv[0]*xv[0] + xv[1]*xv[1] + xv[2]*xv[2] + xv[3]*xv[3];
  #pragma unroll
  for (int o = 1; o < 64; o <<= 1) {
    s  += __shfl_xor(s, o);
    ss += __shfl_xor(ss, o);
  }
  __shared__ float red[8];
  int wave = tid >> 6, lane = tid & 63;
  if (lane == 0) { red[wave] = s; red[4 + wave] = ss; }
  __syncthreads();
  s  = red[0] + red[1] + red[2] + red[3];
  ss = red[4] + red[5] + red[6] + red[7];
  float mu = s * (1.0f / Dd);
  float var = ss * (1.0f / Dd) - mu * mu;
  float rstd = rsqrtf(var + 1e-5f);
  f32x4 gv = *(const f32x4*)(g + tid * 4);
  f32x4 bv = *(const f32x4*)(bb + tid * 4);
  f32x4 y;
  #pragma unroll
  for (int j = 0; j < 4; ++j) y[j] = (xv[j] - mu) * rstd * gv[j] + bv[j];
  *(f32x4*)(hout + off) = y;
  u16x4 yb = { f2bf(y[0]), f2bf(y[1]), f2bf(y[2]), f2bf(y[3]) };
  *(u16x4*)(hbout + off) = yb;
}

// ---------------- residual + split-K partial reduce + bias + LayerNorm ----------------
__global__ __launch_bounds__(256) void add_ln_red_kernel(
    const float* __restrict__ hin, const float* __restrict__ parts,
    const float* __restrict__ bias2,
    const float* __restrict__ g, const float* __restrict__ bb,
    float* __restrict__ hout, unsigned short* __restrict__ hbout) {
  int row = blockIdx.x;
  int tid = threadIdx.x;
  size_t off = (size_t)row * Dd + tid * 4;
  f32x4 xv = *(const f32x4*)(hin + off);
  xv += *(const f32x4*)(bias2 + tid * 4);
  #pragma unroll
  for (int s = 0; s < KSPLIT; ++s)
    xv += *(const f32x4*)(parts + (size_t)s * Mm * Dd + off);
  float s  = xv[0] + xv[1] + xv[2] + xv[3];
  float ss = xv[0]*xv[0] + xv[1]*xv[1] + xv[2]*xv[2] + xv[3]*xv[3];
  #pragma unroll
  for (int o = 1; o < 64; o <<= 1) {
    s  += __shfl_xor(s, o);
    ss += __shfl_xor(ss, o);
  }
  __shared__ float red[8];
  int wave = tid >> 6, lane = tid & 63;
  if (lane == 0) { red[wave] = s; red[4 + wave] = ss; }
  __syncthreads();
  s  = red[0] + red[1] + red[2] + red[3];
  ss = red[4] + red[5] + red[6] + red[7];
  float mu = s * (1.0f / Dd);
  float var = ss * (1.0f / Dd) - mu * mu;
  float rstd = rsqrtf(var + 1e-5f);
  f32x4 gv = *(const f32x4*)(g + tid * 4);
  f32x4 bv = *(const f32x4*)(bb + tid * 4);
  f32x4 y;
  #pragma unroll
  for (int j = 0; j < 4; ++j) y[j] = (xv[j] - mu) * rstd * gv[j] + bv[j];
  *(f32x4*)(hout + off) = y;
  u16x4 yb = { f2bf(y[0]), f2bf(y[1]), f2bf(y[2]), f2bf(y[3]) };
  *(u16x4*)(hbout + off) = yb;
}

// ---------------- QKV split-K reduce + bias -> bf16 ----------------
// grid (3, Mm): blockIdx.x = 1024-col segment, blockIdx.y = row
__global__ __launch_bounds__(256) void qkv_red_kernel(
    const float* __restrict__ qp, const float* __restrict__ cbl,
    unsigned short* __restrict__ qkvout) {
  int row = blockIdx.y;
  int col = blockIdx.x * 1024 + threadIdx.x * 4;
  size_t off = (size_t)row * 3072 + col;
  f32x4 v = *(const f32x4*)(qp + off);
  #pragma unroll
  for (int s = 1; s < QSPLIT; ++s)
    v += *(const f32x4*)(qp + (size_t)s * Mm * 3072 + off);
  v += *(const f32x4*)(cbl + col);
  u16x4 o = { f2bf(v[0]), f2bf(v[1]), f2bf(v[2]), f2bf(v[3]) };
  *(u16x4*)(qkvout + off) = o;
}

// ---------------- bias gather: cb[l] = [bq|bk|bv] ----------------
__global__ __launch_bounds__(256) void bias_gather_kernel(
    const float* __restrict__ bq, const float* __restrict__ bk,
    const float* __restrict__ bv, float* __restrict__ cb) {
  int l = blockIdx.x;
  int i = threadIdx.x * 4;
  f32x4 q = *(const f32x4*)(bq + (size_t)l * Dd + i);
  f32x4 k = *(const f32x4*)(bk + (size_t)l * Dd + i);
  f32x4 v = *(const f32x4*)(bv + (size_t)l * Dd + i);
  *(f32x4*)(cb + (size_t)l * 3072 + i) = q;
  *(f32x4*)(cb + (size_t)l * 3072 + 1024 + i) = k;
  *(f32x4*)(cb + (size_t)l * 3072 + 2048 + i) = v;
}

// ---------------- weight transpose + fp32->bf16: W[K][N] -> Wt[N][K], batched over z ----------------
__global__ __launch_bounds__(256) void tconv_kernel(
    const float* __restrict__ W, unsigned short* __restrict__ Wt,
    int K, int N, int Nvalid, size_t sW, size_t sWt) {
  const float* Wl = W + (size_t)blockIdx.z * sW;
  unsigned short* Wtl = Wt + (size_t)blockIdx.z * sWt;
  __shared__ unsigned short t[64][72];
  int n0 = blockIdx.x * 64, k0 = blockIdx.y * 64;
  int tx = threadIdx.x & 15, ty = threadIdx.x >> 4;  // 16x16
  #pragma unroll
  for (int i = 0; i < 4; ++i) {
    int kr = ty + i * 16;
    int nc = tx * 4;
    int gn = n0 + nc;
    f32x4 v = {0.f, 0.f, 0.f, 0.f};
    if (gn + 3 < Nvalid) {
      v = *(const f32x4*)(Wl + (size_t)(k0 + kr) * N + gn);
    } else {
      #pragma unroll
      for (int j = 0; j < 4; ++j)
        if (gn + j < Nvalid) v[j] = Wl[(size_t)(k0 + kr) * N + gn + j];
    }
    t[nc + 0][kr] = f2bf(v[0]); t[nc + 1][kr] = f2bf(v[1]);
    t[nc + 2][kr] = f2bf(v[2]); t[nc + 3][kr] = f2bf(v[3]);
  }
  __syncthreads();
  #pragma unroll
  for (int i = 0; i < 4; ++i) {
    int nr = ty + i * 16;
    u16x4 o = *(const u16x4*)&t[nr][tx * 4];
    *(u16x4*)(Wtl + (size_t)(n0 + nr) * K + k0 + tx * 4) = o;
  }
}

// ---------------- GEMM (m97 + 2-phase dbuf), wave tiling + split-K + T2 swizzle ----------
// C[M,Ncols] = A[M][K](bf16) * Bt[N][K](bf16)^T (+ bias unless EPI==3).
// grid (M/BM, ceil(N/BN), KS); per-block K-slice = K/KS.
// LDS layout: [row][16B-slot] with slot ^= (row>>1)&3 -- both-sides involution
// (pre-swizzled per-lane GLOBAL source since global_load_lds writes linearly;
// reads apply the same XOR). Spreads 16-lane fragment reads over 8 banks:
// 8-way conflict -> 2-way (free).
// EPI: 0 = fp32+bias, 1 = bf16+bias, 2 = gelu->bf16+bias,
//      3 = fp32 PARTIAL (no bias) at Cout + blockIdx.z*zstr.
// SWZ: bijective XCD-ownership swizzle (grid total % 8 == 0), >L3 working sets.
template <int BM, int BN, int WR, int WC, int EPI, bool SWZ, int KS>
__global__ __launch_bounds__(256) void gemm_bt(
    const unsigned short* __restrict__ A, const unsigned short* __restrict__ Bt,
    const float* __restrict__ bias, void* __restrict__ Cout,
    int Ncols, int K, size_t zstr) {
  static_assert(WR * WC == 4, "4 waves");
  constexpr int MI = BM / WR / 16;
  constexpr int NJ = BN / WC / 16;
  __shared__ __align__(16) unsigned short Al[2][BM * 32];
  __shared__ __align__(16) unsigned short Bl[2][BN * 32];
  int bx = blockIdx.x, by = blockIdx.y;
  if constexpr (SWZ) {
    unsigned gx = gridDim.x;
    unsigned total = gx * gridDim.y;
    unsigned flat = by * gx + bx;           // dispatch order (x fastest)
    unsigned per = total >> 3;
    unsigned work = (flat & 7u) * per + (flat >> 3);
    bx = work % gx; by = work / gx;
  }
  const int bm = bx * BM;
  const int bn = by * BN;
  const int tid = threadIdx.x, lane = tid & 63, wave = tid >> 6;
  const int wm = (wave / WC) * (BM / WR);
  const int wn = (wave % WC) * (BN / WC);
  const int rowi = lane >> 2;                      // row within 16-row chunk
  const int kswz = ((lane & 3) ^ ((rowi >> 1) & 3)) * 8;  // pre-swizzled global k (u16)

  auto stage = [&](int buf, int k0) {
    #pragma unroll
    for (int i = 0; i < BM / 64; ++i) {
      int ch = wave + i * 4;
      async_cp16(A + (size_t)(bm + ch * 16 + rowi) * K + k0 + kswz, &Al[buf][ch * 512]);
    }
    #pragma unroll
    for (int i = 0; i < BN / 64; ++i) {
      int ch = wave + i * 4;
      async_cp16(Bt + (size_t)(bn + ch * 16 + rowi) * K + k0 + kswz, &Bl[buf][ch * 512]);
    }
  };

  f32x4 acc[MI][NJ];
  #pragma unroll
  for (int i = 0; i < MI; ++i)
    #pragma unroll
    for (int j = 0; j < NJ; ++j) acc[i][j] = {0.f, 0.f, 0.f, 0.f};

  const int kbeg = (KS > 1) ? (int)blockIdx.z * (K / KS) : 0;
  const int kend = kbeg + K / KS;

  stage(0, kbeg);
  __syncthreads();            // implicit vmcnt(0): tile 0 resident
  int cur = 0;
  for (int k0 = kbeg; k0 < kend; k0 += 32) {
    if (k0 + 32 < kend) stage(cur ^ 1, k0 + 32);  // prefetch under ds_read+MFMA
    u16x8 af[MI], bfr[NJ];
    #pragma unroll
    for (int i = 0; i < MI; ++i) {
      int ar = wm + i * 16 + (lane & 15);
      int sl = (lane >> 4) ^ ((ar >> 1) & 3);     // same involution as source
      af[i] = *(const u16x8*)&Al[cur][ar * 32 + sl * 8];
    }
    #pragma unroll
    for (int j = 0; j < NJ; ++j) {
      int br = wn + j * 16 + (lane & 15);
      int sl = (lane >> 4) ^ ((br >> 1) & 3);
      bfr[j] = *(const u16x8*)&Bl[cur][br * 32 + sl * 8];
    }
    #pragma unroll
    for (int i = 0; i < MI; ++i)
      #pragma unroll
      for (int j = 0; j < NJ; ++j)
        acc[i][j] = mfma16x16x32(af[i], bfr[j], acc[i][j]);
    __syncthreads();          // drains vmcnt(0) (next tile landed) + read-safety
    cur ^= 1;
  }

  // epilogue: C/D layout col=lane&15, row=(lane>>4)*4+reg
  float bvv[NJ];
  #pragma unroll
  for (int j = 0; j < NJ; ++j) {
    if constexpr (EPI != 3) {
      int col = bn + wn + j * 16 + (lane & 15);
      bvv[j] = (col < Ncols) ? bias[col] : 0.0f;
    } else bvv[j] = 0.0f;
  }
  float* Cz = (EPI == 3) ? ((float*)Cout + (size_t)blockIdx.z * zstr) : (float*)Cout;
  #pragma unroll
  for (int i = 0; i < MI; ++i) {
    #pragma unroll
    for (int rr = 0; rr < 4; ++rr) {
      int row = bm + wm + i * 16 + (lane >> 4) * 4 + rr;
      #pragma unroll
      for (int j = 0; j < NJ; ++j) {
        int col = bn + wn + j * 16 + (lane & 15);
        if (col < Ncols) {
          float val = acc[i][j][rr] + bvv[j];
          if constexpr (EPI == 0) {
            ((float*)Cout)[(size_t)row * Ncols + col] = val;
          } else if constexpr (EPI == 1) {
            ((unsigned short*)Cout)[(size_t)row * Ncols + col] = f2bf(val);
          } else if constexpr (EPI == 2) {
            float gv = 0.5f * val * (1.0f + erff(val * 0.70710678f));
            ((unsigned short*)Cout)[(size_t)row * Ncols + col] = f2bf(gv);
          } else {
            Cz[(size_t)row * Ncols + col] = val;
          }
        }
      }
    }
  }
}

// ---------------- legacy GEMM (fp32 B, staged convert) -- small-ws fallback ----------------
template <int EPI>
__global__ __launch_bounds__(256) void gemm_f32b(
    const unsigned short* __restrict__ A, const float* __restrict__ Bw,
    const float* __restrict__ bias, void* __restrict__ Cout, int N, int K) {
  __shared__ __align__(16) unsigned short Al[128][40];
  __shared__ __align__(16) unsigned short Btl[128][40];
  const int bn = blockIdx.x * 128;
  const int bm = blockIdx.y * 128;
  const int tid = threadIdx.x;
  const int lane = tid & 63;
  const int wave = tid >> 6;
  const int wm = (wave >> 1) * 64;
  const int wn = (wave & 1) * 64;
  const bool nfast = ((N & 3) == 0);

  f32x4 acc[4][4];
  #pragma unroll
  for (int i = 0; i < 4; ++i)
    #pragma unroll
    for (int j = 0; j < 4; ++j) acc[i][j] = {0.f, 0.f, 0.f, 0.f};

  for (int k0 = 0; k0 < K; k0 += 32) {
    __syncthreads();
    #pragma unroll
    for (int i = 0; i < 2; ++i) {
      int c = tid + i * 256;
      int row = c >> 2, ko = (c & 3) * 8;
      u16x8 v = *(const u16x8*)(A + (size_t)(bm + row) * K + k0 + ko);
      *(u16x8*)&Al[row][ko] = v;
    }
    if (nfast) {
      #pragma unroll
      for (int i = 0; i < 4; ++i) {
        int c = tid + i * 256;
        int kr = c >> 5;
        int no = (c & 31) * 4;
        f32x4 v4 = *(const f32x4*)(Bw + (size_t)(k0 + kr) * N + bn + no);
        Btl[no + 0][kr] = f2bf(v4[0]); Btl[no + 1][kr] = f2bf(v4[1]);
        Btl[no + 2][kr] = f2bf(v4[2]); Btl[no + 3][kr] = f2bf(v4[3]);
      }
    } else {
      #pragma unroll
      for (int i = 0; i < 4; ++i) {
        int c = tid + i * 256;
        int kr = c >> 5;
        int nb = c & 31;
        #pragma unroll
        for (int j = 0; j < 4; ++j) {
          int col = nb + j * 32;
          float v = (bn + col < N) ? Bw[(size_t)(k0 + kr) * N + bn + col] : 0.0f;
          Btl[col][kr] = f2bf(v);
        }
      }
    }
    __syncthreads();
    u16x8 af[4], bfr[4];
    #pragma unroll
    for (int i = 0; i < 4; ++i)
      af[i] = *(const u16x8*)&Al[wm + i * 16 + (lane & 15)][(lane >> 4) * 8];
    #pragma unroll
    for (int j = 0; j < 4; ++j)
      bfr[j] = *(const u16x8*)&Btl[wn + j * 16 + (lane & 15)][(lane >> 4) * 8];
    #pragma unroll
    for (int i = 0; i < 4; ++i)
      #pragma unroll
      for (int j = 0; j < 4; ++j)
        acc[i][j] = mfma16x16x32(af[i], bfr[j], acc[i][j]);
  }
  #pragma unroll
  for (int j = 0; j < 4; ++j) {
    int col = bn + wn + j * 16 + (lane & 15);
    bool cok = (col < N);
    float bv = cok ? bias[col] : 0.0f;
    #pragma unroll
    for (int i = 0; i < 4; ++i) {
      #pragma unroll
      for (int rr = 0; rr < 4; ++rr) {
        int row = bm + wm + i * 16 + (lane >> 4) * 4 + rr;
        float val = acc[i][j][rr] + bv;
        if (cok) {
          if constexpr (EPI == 0) ((float*)Cout)[(size_t)row * N + col] = val;
          else if constexpr (EPI == 1) ((unsigned short*)Cout)[(size_t)row * N + col] = f2bf(val);
          else {
            float gv = 0.5f * val * (1.0f + erff(val * 0.70710678f));
            ((unsigned short*)Cout)[(size_t)row * N + col] = f2bf(gv);
          }
        }
      }
    }
  }
}

// ---------------- fused causal attention (R4 version, known-good) ----------------
__global__ __launch_bounds__(256) void attn_kernel(
    const unsigned short* __restrict__ q, const unsigned short* __restrict__ k,
    const unsigned short* __restrict__ v, float* __restrict__ o, int ld) {
  const int ys = blockIdx.y;
  const int qt = (ys < 8) ? ys : 23 - ys;  // pairing remap (bijective on 0..15)
  const int bh = blockIdx.x;
  const int b = bh >> 4, h = bh & 15;
  const size_t base = (size_t)b * Tt * ld + (size_t)h * 64;
  const int tid = threadIdx.x, lane = tid & 63, wave = tid >> 6;
  const int q0 = qt * 64 + wave * 16;

  __shared__ __align__(16) unsigned short Kl[64][72];
  __shared__ __align__(16) unsigned short Vt[64][72];   // [d][kc swizzled]
  __shared__ __align__(16) unsigned short Pl[4][16][72];

  const float SC = 0.18033688011112042f;  // 0.125 * log2(e)

  u16x8 qa[2];
  {
    const unsigned short* qp = q + base + (size_t)(q0 + (lane & 15)) * ld + (lane >> 4) * 8;
    qa[0] = *(const u16x8*)qp;
    qa[1] = *(const u16x8*)(qp + 32);
  }

  f32x4 Oacc[4];
  #pragma unroll
  for (int df = 0; df < 4; ++df) Oacc[df] = {0.f, 0.f, 0.f, 0.f};
  float m_run[4], l_run[4];
  #pragma unroll
  for (int rr = 0; rr < 4; ++rr) { m_run[rr] = -__builtin_inff(); l_run[rr] = 0.f; }

  for (int kt = 0; kt <= qt; ++kt) {
    __syncthreads();
    #pragma unroll
    for (int i = 0; i < 2; ++i) {
      int c = tid + i * 256;
      int rr = c >> 3, dof = (c & 7) * 8;
      *(u16x8*)&Kl[rr][dof] =
          *(const u16x8*)(k + base + (size_t)(kt * 64 + rr) * ld + dof);
    }
    #pragma unroll
    for (int i = 0; i < 2; ++i) {
      int c = tid + i * 256;
      int rr = c >> 3, dof = (c & 7) * 8;
      u16x8 vv = *(const u16x8*)(v + base + (size_t)(kt * 64 + rr) * ld + dof);
      #pragma unroll
      for (int j = 0; j < 8; ++j) {
        int d = dof + j;
        Vt[d][(rr + (d & 56)) & 63] = vv[j];
      }
    }
    __syncthreads();

    f32x4 S[4];
    #pragma unroll
    for (int nf = 0; nf < 4; ++nf) {
      S[nf] = {0.f, 0.f, 0.f, 0.f};
      #pragma unroll
      for (int s = 0; s < 2; ++s) {
        u16x8 kb = *(const u16x8*)&Kl[nf * 16 + (lane & 15)][s * 32 + (lane >> 4) * 8];
        S[nf] = mfma16x16x32(qa[s], kb, S[nf]);
      }
    }
    const int kbase = kt * 64;
    float mx[4];
    #pragma unroll
    for (int rr = 0; rr < 4; ++rr) mx[rr] = -__builtin_inff();
    #pragma unroll
    for (int nf = 0; nf < 4; ++nf) {
      int kcol = kbase + nf * 16 + (lane & 15);
      #pragma unroll
      for (int rr = 0; rr < 4; ++rr) {
        int qrow = q0 + (lane >> 4) * 4 + rr;
        float sv = S[nf][rr] * SC;
        if (kcol > qrow) sv = -__builtin_inff();
        S[nf][rr] = sv;
        mx[rr] = fmaxf(mx[rr], sv);
      }
    }
    #pragma unroll
    for (int rr = 0; rr < 4; ++rr) {
      #pragma unroll
      for (int off = 1; off < 16; off <<= 1)
        mx[rr] = fmaxf(mx[rr], __shfl_xor(mx[rr], off));
    }
    float psum[4];
    #pragma unroll
    for (int rr = 0; rr < 4; ++rr) {
      float mnew = fmaxf(m_run[rr], mx[rr]);
      float sc = exp2f(m_run[rr] - mnew);
      l_run[rr] *= sc;
      #pragma unroll
      for (int df = 0; df < 4; ++df) Oacc[df][rr] *= sc;
      m_run[rr] = mnew;
      psum[rr] = 0.f;
    }
    #pragma unroll
    for (int nf = 0; nf < 4; ++nf) {
      #pragma unroll
      for (int rr = 0; rr < 4; ++rr) {
        float pv = exp2f(S[nf][rr] - m_run[rr]);
        S[nf][rr] = pv;
        psum[rr] += pv;
      }
    }
    #pragma unroll
    for (int rr = 0; rr < 4; ++rr) {
      #pragma unroll
      for (int off = 1; off < 16; off <<= 1) psum[rr] += __shfl_xor(psum[rr], off);
      l_run[rr] += psum[rr];
    }
    #pragma unroll
    for (int nf = 0; nf < 4; ++nf)
      #pragma unroll
      for (int rr = 0; rr < 4; ++rr)
        Pl[wave][(lane >> 4) * 4 + rr][nf * 16 + (lane & 15)] = f2bf(S[nf][rr]);
    __syncthreads();
    #pragma unroll
    for (int s = 0; s < 2; ++s) {
      u16x8 pa = *(const u16x8*)&Pl[wave][lane & 15][s * 32 + (lane >> 4) * 8];
      #pragma unroll
      for (int df = 0; df < 4; ++df) {
        int d = df * 16 + (lane & 15);
        int cs = (s * 32 + (lane >> 4) * 8 + (d & 56)) & 63;
        u16x8 vb = *(const u16x8*)&Vt[d][cs];
        Oacc[df] = mfma16x16x32(pa, vb, Oacc[df]);
      }
    }
  }

  #pragma unroll
  for (int df = 0; df < 4; ++df) {
    int d = df * 16 + (lane & 15);
    #pragma unroll
    for (int rr = 0; rr < 4; ++rr) {
      int qrow = q0 + (lane >> 4) * 4 + rr;
      o[((size_t)b * Tt + qrow) * Dd + h * 64 + d] = Oacc[df][rr] / l_run[rr];
    }
  }
}

// ---------------- host launch ----------------
extern "C" void kernel_launch(void* const* d_in, const int* in_sizes, int n_in,
                              void* d_out, int out_size, void* d_ws, size_t ws_size,
                              hipStream_t stream) {
  const int*   x     = (const int*)d_in[0];
  const float* emb   = (const float*)d_in[1];
  const float* pos   = (const float*)d_in[2];
  const float* Wq    = (const float*)d_in[3];
  const float* bq    = (const float*)d_in[4];
  const float* Wk    = (const float*)d_in[5];
  const float* bk    = (const float*)d_in[6];
  const float* Wv    = (const float*)d_in[7];
  const float* bv    = (const float*)d_in[8];
  const float* ln_g  = (const float*)d_in[9];
  const float* ln_b  = (const float*)d_in[10];
  const float* W1    = (const float*)d_in[11];
  const float* b1    = (const float*)d_in[12];
  const float* W2    = (const float*)d_in[13];
  const float* b2    = (const float*)d_in[14];
  const float* lnf_g = (const float*)d_in[15];
  const float* lnf_b = (const float*)d_in[16];
  const float* Wout  = (const float*)d_in[17];
  const float* bout  = (const float*)d_in[18];
  float* out = (float*)d_out;

  char* p = (char*)d_ws;
  auto alloc = [&](size_t bytes) {
    char* r = p; p += (bytes + 255) & ~(size_t)255; return r;
  };
  float* h           = (float*)alloc((size_t)Mm * Dd * 4);
  unsigned short* hb = (unsigned short*)alloc((size_t)Mm * Dd * 2);
  unsigned short* qkv = (unsigned short*)alloc((size_t)Mm * 3072 * 2);
  float* of          = (float*)alloc((size_t)Mm * Dd * 4);
  unsigned short* a1 = (unsigned short*)alloc((size_t)Mm * Ff * 2);
  float* cb          = (float*)alloc((size_t)Ll * 3072 * 4);
  float* parts       = (float*)alloc((size_t)KSPLIT * Mm * Dd * 4);   // FFN2 split-K
  float* qparts      = (float*)alloc((size_t)QSPLIT * Mm * 3072 * 4); // QKV split-K
  size_t base_used = (size_t)(p - (char*)d_ws);

  const size_t SZ_WQKVT = (size_t)Ll * 3072 * Dd * 2;
  const size_t SZ_W1T   = (size_t)Ll * Ff * Dd * 2;
  const size_t SZ_W2T   = (size_t)Ll * Dd * Ff * 2;
  const size_t SZ_WOUTT = (size_t)Va * Dd * 2;
  const size_t need_big = base_used + SZ_WQKVT + SZ_W1T + SZ_W2T + SZ_WOUTT + 4096;
  const size_t need_rot = base_used + SZ_WOUTT + 4096;

  embed_kernel<<<Mm, 256, 0, stream>>>(x, emb, pos, h, hb);

  if (ws_size >= need_rot) {
    bias_gather_kernel<<<Ll, 256, 0, stream>>>(bq, bk, bv, cb);
    const bool big = (ws_size >= need_big);
    unsigned short *wqkvt, *w1t, *w2t, *woutt;
    if (big) {
      wqkvt = (unsigned short*)alloc(SZ_WQKVT);
      w1t   = (unsigned short*)alloc(SZ_W1T);
      w2t   = (unsigned short*)alloc(SZ_W2T);
      woutt = (unsigned short*)alloc(SZ_WOUTT);
      tconv_kernel<<<dim3(16, 16, Ll), 256, 0, stream>>>(
          Wq, wqkvt,           Dd, Dd, Dd, (size_t)Dd*Dd, (size_t)3072*Dd);
      tconv_kernel<<<dim3(16, 16, Ll), 256, 0, stream>>>(
          Wk, wqkvt + 1024*Dd, Dd, Dd, Dd, (size_t)Dd*Dd, (size_t)3072*Dd);
      tconv_kernel<<<dim3(16, 16, Ll), 256, 0, stream>>>(
          Wv, wqkvt + 2048*Dd, Dd, Dd, Dd, (size_t)Dd*Dd, (size_t)3072*Dd);
      tconv_kernel<<<dim3(Ff/64, Dd/64, Ll), 256, 0, stream>>>(
          W1, w1t, Dd, Ff, Ff, (size_t)Dd*Ff, (size_t)Ff*Dd);
      tconv_kernel<<<dim3(Dd/64, Ff/64, Ll), 256, 0, stream>>>(
          W2, w2t, Ff, Dd, Dd, (size_t)Ff*Dd, (size_t)Dd*Ff);
      tconv_kernel<<<dim3(Va/64, Dd/64, 1), 256, 0, stream>>>(
          Wout, woutt, Dd, Vv, Vv, 0, 0);
    } else {
      unsigned short* wbuf = (unsigned short*)alloc(SZ_WOUTT);
      wqkvt = w1t = w2t = woutt = wbuf;
    }

    for (int l = 0; l < Ll; ++l) {
      unsigned short* wq_l = big ? (wqkvt + (size_t)l * 3072 * Dd) : wqkvt;
      if (!big) {
        tconv_kernel<<<dim3(16, 16, 1), 256, 0, stream>>>(Wq + (size_t)l * Dd * Dd, wq_l,           Dd, Dd, Dd, 0, 0);
        tconv_kernel<<<dim3(16, 16, 1), 256, 0, stream>>>(Wk + (size_t)l * Dd * Dd, wq_l + 1024*Dd, Dd, Dd, Dd, 0, 0);
        tconv_kernel<<<dim3(16, 16, 1), 256, 0, stream>>>(Wv + (size_t)l * Dd * Dd, wq_l + 2048*Dd, Dd, Dd, Dd, 0, 0);
      }
      // QKV: split-K=2, grid 16x24x2 = 768 blocks (3/CU balanced), K=512/slice
      gemm_bt<128, 128, 2, 2, 3, false, QSPLIT><<<dim3(Mm/128, 3072/128, QSPLIT), 256, 0, stream>>>(
          hb, wq_l, nullptr, qparts, 3072, Dd, (size_t)Mm * 3072);
      qkv_red_kernel<<<dim3(3, Mm), 256, 0, stream>>>(qparts, cb + (size_t)l * 3072, qkv);
      attn_kernel<<<dim3(Bb*Hh, Tt/64), 256, 0, stream>>>(qkv, qkv + 1024, qkv + 2048, of, 3072);
      add_ln_kernel<<<Mm, 256, 0, stream>>>(h, of, ln_g + (size_t)l * Dd,
                                            ln_b + (size_t)l * Dd, h, hb);
      unsigned short* w1_l = big ? (w1t + (size_t)l * Ff * Dd) : w1t;
      if (!big)
        tconv_kernel<<<dim3(Ff/64, Dd/64, 1), 256, 0, stream>>>(W1 + (size_t)l * Dd * Ff, w1_l, Dd, Ff, Ff, 0, 0);
      // FFN1: 128x128, grid 16x32 = 512 blocks
      gemm_bt<128, 128, 2, 2, 2, false, 1><<<dim3(Mm/128, Ff/128), 256, 0, stream>>>(
          hb, w1_l, b1 + (size_t)l * Ff, a1, Ff, Dd, 0);
      unsigned short* w2_l = big ? (w2t + (size_t)l * Dd * Ff) : w2t;
      if (!big)
        tconv_kernel<<<dim3(Dd/64, Ff/64, 1), 256, 0, stream>>>(W2 + (size_t)l * Ff * Dd, w2_l, Ff, Dd, Dd, 0, 0);
      // FFN2: split-K=4, 128x128 tiles, grid 16x8x4 = 512 blocks, K=1024/slice
      gemm_bt<128, 128, 2, 2, 3, false, KSPLIT><<<dim3(Mm/128, Dd/128, KSPLIT), 256, 0, stream>>>(
          a1, w2_l, nullptr, parts, Dd, Ff, (size_t)Mm * Dd);
      // fused: h = LN(h + sum(parts) + b2)
      add_ln_red_kernel<<<Mm, 256, 0, stream>>>(h, parts, b2 + (size_t)l * Dd,
                                                ln_g + (size_t)l * Dd,
                                                ln_b + (size_t)l * Dd, h, hb);
    }

    add_ln_kernel<<<Mm, 256, 0, stream>>>(h, nullptr, lnf_g, lnf_b, h, hb);
    if (!big)
      tconv_kernel<<<dim3(Va/64, Dd/64, 1), 256, 0, stream>>>(Wout, woutt, Dd, Vv, Vv, 0, 0);
    // logits: 128x128 + XCD-ownership swizzle (grid 16x393 = 6288, %8==0)
    gemm_bt<128, 128, 2, 2, 0, true, 1><<<dim3(Mm/128, Va/128), 256, 0, stream>>>(
        hb, woutt, bout, out, Vv, Dd, 0);
  } else {
    unsigned short* qb = qkv;
    unsigned short* kb = qkv + (size_t)Mm * Dd;
    unsigned short* vb = qkv + (size_t)2 * Mm * Dd;
    for (int l = 0; l < Ll; ++l) {
      const size_t wo = (size_t)l * Dd * Dd;
      gemm_f32b<1><<<dim3(Dd/128, Mm/128), 256, 0, stream>>>(hb, Wq + wo, bq + (size_t)l*Dd, qb, Dd, Dd);
      gemm_f32b<1><<<dim3(Dd/128, Mm/128), 256, 0, stream>>>(hb, Wk + wo, bk + (size_t)l*Dd, kb, Dd, Dd);
      gemm_f32b<1><<<dim3(Dd/128, Mm/128), 256, 0, stream>>>(hb, Wv + wo, bv + (size_t)l*Dd, vb, Dd, Dd);
      attn_kernel<<<dim3(Bb*Hh, Tt/64), 256, 0, stream>>>(qb, kb, vb, of, Dd);
      add_ln_kernel<<<Mm, 256, 0, stream>>>(h, of, ln_g + (size_t)l*Dd, ln_b + (size_t)l*Dd, h, hb);
      gemm_f32b<2><<<dim3(Ff/128, Mm/128), 256, 0, stream>>>(hb, W1 + (size_t)l*Dd*Ff, b1 + (size_t)l*Ff, a1, Ff, Dd);
      gemm_f32b<0><<<dim3(Dd/128, Mm/128), 256, 0, stream>>>(a1, W2 + (size_t)l*Ff*Dd, b2 + (size_t)l*Dd, of, Dd, Ff);
      add_ln_kernel<<<Mm, 256, 0, stream>>>(h, of, ln_g + (size_t)l*Dd, ln_b + (size_t)l*Dd, h, hb);
    }
    add_ln_kernel<<<Mm, 256, 0, stream>>>(h, nullptr, lnf_g, lnf_b, h, hb);
    gemm_f32b<0><<<dim3((Vv + 127)/128, Mm/128), 256, 0, stream>>>(hb, Wout, bout, out, Vv, Dd);
  }
}